// Round 6
// baseline (640.203 us; speedup 1.0000x reference)
//
#include <hip/hip_runtime.h>
#include <hip/hip_bf16.h>
#include <math.h>

#define BSZ 4
#define CH  192
#define NPT 4096
#define KNB 16
#define KPH 20              // kept per half
#define KCAND (2 * KPH)     // refine candidates

typedef short short8 __attribute__((ext_vector_type(8)));
typedef float f32x4  __attribute__((ext_vector_type(4)));

__device__ __forceinline__ float gelu_exact(float x){
    return 0.5f * x * (1.0f + erff(x * 0.70710678118654752440f));
}
__device__ __forceinline__ unsigned int umin_(unsigned int a, unsigned int b){ return a < b ? a : b; }
__device__ __forceinline__ unsigned int umax_(unsigned int a, unsigned int b){ return a < b ? b : a; }

// ---------------- fp32 GEMM: out[b,o,n] = sum_c W[o,c] * in[b,c,n] (+bias)(+BN-fold)(+resid) ----
template<int KDIM, bool BIASED, bool SCALED, bool RESID>
__global__ __launch_bounds__(256) void k_gemm(
    const float* __restrict__ in, const float* __restrict__ W,
    const float* __restrict__ bias, const float* __restrict__ sc,
    const float* __restrict__ sh, const float* __restrict__ resid,
    float* __restrict__ out)
{
    constexpr int OT = 8, NT = 4;
    __shared__ float wtT[KDIM][OT];
    __shared__ float scl[SCALED ? KDIM : 1];
    __shared__ float shl[SCALED ? KDIM : 1];
    const int tid = threadIdx.x;
    const int o0  = blockIdx.y * OT;
    const int b   = blockIdx.z;
    const int n   = blockIdx.x * (256 * NT) + tid * NT;

    for (int lin = tid; lin < KDIM * OT; lin += 256){
        int c = lin >> 3, o = lin & 7;
        wtT[c][o] = W[(size_t)(o0 + o) * KDIM + c];
    }
    if (SCALED){
        for (int c = tid; c < KDIM; c += 256){ scl[c] = sc[c]; shl[c] = sh[c]; }
    }
    __syncthreads();

    float acc[OT][NT] = {};
    const float* ip = in + (size_t)b * KDIM * NPT + n;
    #pragma unroll 2
    for (int c = 0; c < KDIM; ++c){
        float4 x4 = *reinterpret_cast<const float4*>(ip + (size_t)c * NPT);
        float xv[NT] = {x4.x, x4.y, x4.z, x4.w};
        if (SCALED){
            #pragma unroll
            for (int j = 0; j < NT; ++j) xv[j] = fmaf(xv[j], scl[c], shl[c]);
        }
        float4 w0 = *reinterpret_cast<const float4*>(&wtT[c][0]);
        float4 w1 = *reinterpret_cast<const float4*>(&wtT[c][4]);
        float wv[OT] = {w0.x, w0.y, w0.z, w0.w, w1.x, w1.y, w1.z, w1.w};
        #pragma unroll
        for (int oo = 0; oo < OT; ++oo)
            #pragma unroll
            for (int j = 0; j < NT; ++j)
                acc[oo][j] = fmaf(wv[oo], xv[j], acc[oo][j]);
    }

    #pragma unroll
    for (int oo = 0; oo < OT; ++oo){
        size_t off = ((size_t)b * CH + o0 + oo) * NPT + n;
        float add = BIASED ? bias[o0 + oo] : 0.0f;
        float vals[4];
        #pragma unroll
        for (int j = 0; j < 4; ++j) vals[j] = acc[oo][j] + add;
        if (RESID){
            float4 r4 = *reinterpret_cast<const float4*>(resid + off);
            vals[0] += r4.x; vals[1] += r4.y; vals[2] += r4.z; vals[3] += r4.w;
        }
        float4 o4; o4.x = vals[0]; o4.y = vals[1]; o4.z = vals[2]; o4.w = vals[3];
        *reinterpret_cast<float4*>(out + off) = o4;
    }
}

// ---------------- fc1 with f64 accumulation: writes fp32 t1 and f64 t1 --------------------------
__global__ __launch_bounds__(256) void k_fc1_f64(
    const float* __restrict__ in, const float* __restrict__ W,
    float* __restrict__ outf, double* __restrict__ outd)
{
    constexpr int OT = 8, NT = 4;
    __shared__ float wtT[CH][OT];
    const int tid = threadIdx.x;
    const int o0  = blockIdx.y * OT;
    const int b   = blockIdx.z;
    const int n   = blockIdx.x * (256 * NT) + tid * NT;

    for (int lin = tid; lin < CH * OT; lin += 256){
        int c = lin >> 3, o = lin & 7;
        wtT[c][o] = W[(size_t)(o0 + o) * CH + c];
    }
    __syncthreads();

    double acc[OT][NT] = {};
    const float* ip = in + (size_t)b * CH * NPT + n;
    for (int c = 0; c < CH; ++c){
        float4 x4 = *reinterpret_cast<const float4*>(ip + (size_t)c * NPT);
        double xv[NT] = {x4.x, x4.y, x4.z, x4.w};
        float4 w0 = *reinterpret_cast<const float4*>(&wtT[c][0]);
        float4 w1 = *reinterpret_cast<const float4*>(&wtT[c][4]);
        double wv[OT] = {w0.x, w0.y, w0.z, w0.w, w1.x, w1.y, w1.z, w1.w};
        #pragma unroll
        for (int oo = 0; oo < OT; ++oo)
            #pragma unroll
            for (int j = 0; j < NT; ++j)
                acc[oo][j] = fma(wv[oo], xv[j], acc[oo][j]);
    }

    #pragma unroll
    for (int oo = 0; oo < OT; ++oo){
        size_t off = ((size_t)b * CH + o0 + oo) * NPT + n;
        #pragma unroll
        for (int j = 0; j < 4; ++j){
            outf[off + j] = (float)acc[oo][j];
            outd[off + j] = acc[oo][j];
        }
    }
}

// ---------------- f64 BN0 stats: fp32 scale/shift + f64 scale for kNN ---------------------------
__global__ __launch_bounds__(256) void k_stats_f64(
    const double* __restrict__ t, const float* __restrict__ gamma,
    const float* __restrict__ beta, float* __restrict__ scale,
    float* __restrict__ shift, double* __restrict__ scd)
{
    const int c = blockIdx.x, tid = threadIdx.x;
    double s = 0., s2 = 0.;
    for (int b = 0; b < BSZ; ++b){
        const double* p = t + ((size_t)b * CH + c) * NPT;
        for (int n = tid; n < NPT; n += 256){ double v = p[n]; s += v; s2 += v * v; }
    }
    __shared__ double rs[256], rs2[256];
    rs[tid] = s; rs2[tid] = s2; __syncthreads();
    for (int off = 128; off; off >>= 1){
        if (tid < off){ rs[tid] += rs[tid + off]; rs2[tid] += rs2[tid + off]; }
        __syncthreads();
    }
    if (tid == 0){
        const double invn = 1.0 / (BSZ * NPT);
        double mean = rs[0] * invn;
        double var  = rs2[0] * invn - mean * mean;
        double rstd = 1.0 / sqrt(var + 1e-5);
        double s_   = rstd * (double)gamma[c];
        scale[c] = (float)s_;
        shift[c] = (float)((double)beta[c] - mean * s_);
        scd[c]   = s_;
    }
}

// ---------------- fp32 per-channel batch stats -> scale/shift -----------------------------------
__global__ __launch_bounds__(256) void k_stats(
    const float* __restrict__ t, const float* __restrict__ gamma,
    const float* __restrict__ beta, float* __restrict__ scale, float* __restrict__ shift)
{
    const int c = blockIdx.x, tid = threadIdx.x;
    float s = 0.f, s2 = 0.f;
    for (int b = 0; b < BSZ; ++b){
        const float* p = t + ((size_t)b * CH + c) * NPT;
        for (int n = tid; n < NPT; n += 256){ float v = p[n]; s += v; s2 += v * v; }
    }
    __shared__ float rs[256], rs2[256];
    rs[tid] = s; rs2[tid] = s2; __syncthreads();
    for (int off = 128; off; off >>= 1){
        if (tid < off){ rs[tid] += rs[tid + off]; rs2[tid] += rs2[tid + off]; }
        __syncthreads();
    }
    if (tid == 0){
        const float invn = 1.0f / (BSZ * NPT);
        float mean = rs[0] * invn;
        float var  = rs2[0] * invn - mean * mean;
        float rstd = rsqrtf(var + 1e-5f);
        float s_   = rstd * gamma[c];
        scale[c] = s_;
        shift[c] = beta[c] - mean * s_;
    }
}

// ---------------- transpose + per-channel f64 scale: featT[b][n][c] -----------------------------
__global__ void k_tr64(const double* __restrict__ t1d, const double* __restrict__ scd,
                       double* __restrict__ featT)
{
    __shared__ double tile[32][33];
    const int n0 = blockIdx.x * 32, c0 = blockIdx.y * 32, b = blockIdx.z;
    #pragma unroll
    for (int r = 0; r < 32; r += 8){
        int c = c0 + threadIdx.y + r, n = n0 + threadIdx.x;
        tile[threadIdx.y + r][threadIdx.x] = t1d[((size_t)b * CH + c) * NPT + n] * scd[c];
    }
    __syncthreads();
    #pragma unroll
    for (int r = 0; r < 32; r += 8){
        int n = n0 + threadIdx.y + r, c = c0 + threadIdx.x;
        featT[((size_t)b * NPT + n) * CH + c] = tile[threadIdx.x][threadIdx.y + r];
    }
}

// ---------------- featT (f64, shift-free) -> bf16 features + fp32 sq norms ----------------------
__global__ __launch_bounds__(256) void k_bf_sq(
    const double* __restrict__ featT, unsigned short* __restrict__ featbf,
    float* __restrict__ sqv)
{
    const int wid  = threadIdx.x >> 6;
    const int lane = threadIdx.x & 63;
    const int row  = blockIdx.x * 4 + wid;
    const int b    = blockIdx.y;
    const double* p = featT + ((size_t)b * NPT + row) * CH;
    unsigned short* o = featbf + ((size_t)b * NPT + row) * CH;
    float s = 0.f;
    #pragma unroll
    for (int j = 0; j < 3; ++j){
        float v = (float)p[lane + 64 * j];
        s = fmaf(v, v, s);
        unsigned int bits = __builtin_bit_cast(unsigned int, v);
        o[lane + 64 * j] = (unsigned short)((bits + 0x7fff + ((bits >> 16) & 1)) >> 16);
    }
    #pragma unroll
    for (int off = 32; off; off >>= 1) s += __shfl_xor(s, off);
    if (lane == 0) sqv[b * NPT + row] = s;
}

// ---------------- double-GELU(BN) ----------------------------------------------------------------
__global__ __launch_bounds__(256) void k_u(
    const float* __restrict__ in, const float* __restrict__ sc,
    const float* __restrict__ sh, float* __restrict__ out)
{
    const int c = blockIdx.y, b = blockIdx.z;
    const int n = (blockIdx.x * 256 + threadIdx.x) * 4;
    size_t i = ((size_t)b * CH + c) * NPT + n;
    float4 v = *reinterpret_cast<const float4*>(in + i);
    float s = sc[c], t = sh[c];
    float4 o;
    o.x = gelu_exact(gelu_exact(fmaf(v.x, s, t)));
    o.y = gelu_exact(gelu_exact(fmaf(v.y, s, t)));
    o.z = gelu_exact(gelu_exact(fmaf(v.z, s, t)));
    o.w = gelu_exact(gelu_exact(fmaf(v.w, s, t)));
    *reinterpret_cast<float4*>(out + i) = o;
}

// ---------------- branchless insert of 4 candidates into dual sorted 16-deep key lists ----------
__device__ __forceinline__ void knn_insert4(
    const f32x4& acc, const float4& s4, int m0,
    unsigned int (&Q)[16], unsigned int (&R)[16])
{
    float sa[4] = {s4.x, s4.y, s4.z, s4.w};
    #pragma unroll
    for (int u = 0; u < 4; ++u){
        float d = fmaf(-2.0f, acc[u], sa[u]);
        int bb = __builtin_bit_cast(int, d);
        unsigned int uu = (unsigned int)(bb ^ ((bb >> 31) | 0x80000000));
        unsigned int k  = (uu & 0xFFFFF000u) | (unsigned int)(m0 + u);
        if (u & 1){
            #pragma unroll
            for (int e = 0; e < 16; ++e){
                unsigned int qe = R[e]; R[e] = umin_(k, qe); k = umax_(k, qe);
            }
        } else {
            #pragma unroll
            for (int e = 0; e < 16; ++e){
                unsigned int qe = Q[e]; Q[e] = umin_(k, qe); k = umax_(k, qe);
            }
        }
    }
}

// ---------------- MFMA kNN prefilter v4 -----------------------------------------------------------
// grid (512, BSZ): 256 q-tiles x 2 m-halves. 4 waves/block; wave covers 512 m in 16-m tiles,
// double-buffered loads, dual 16-deep lists per lane (2 chains of ILP). Emits top-20 per half.
// key = sortable-u32(distance) top 20 bits | index (12 bits); globally unique.
__global__ __launch_bounds__(256, 3) void k_knn_mfma(
    const unsigned short* __restrict__ featbf, const float* __restrict__ sqv,
    int* __restrict__ idxh)
{
    __shared__ unsigned int mlist[4][16][KPH + 1];
    const int tid  = threadIdx.x;
    const int wv   = tid >> 6;
    const int lane = tid & 63;
    const int r = lane & 15, g = lane >> 4;
    const int b    = blockIdx.y;
    const int qt   = blockIdx.x >> 1;
    const int half = blockIdx.x & 1;
    const int q0   = qt * 16;
    const int mbase = half * 2048 + wv * 16;
    const unsigned short* fb = featbf + (size_t)b * NPT * CH;

    short8 bq[6];
    {
        const unsigned short* qp = fb + (size_t)(q0 + r) * CH + g * 8;
        #pragma unroll
        for (int ks = 0; ks < 6; ++ks) bq[ks] = *reinterpret_cast<const short8*>(qp + ks * 32);
    }

    unsigned int Q[16], R[16];
    #pragma unroll
    for (int e = 0; e < 16; ++e){ Q[e] = 0xFFFFFFFFu; R[e] = 0xFFFFFFFFu; }

    const float* sq = sqv + b * NPT;
    const unsigned short* pa = fb + (size_t)(mbase + r) * CH + g * 8;
    constexpr size_t STP = (size_t)64 * CH;   // m-stride per iteration (4 waves x 16)
    constexpr int NIT = 32;

    short8 a_[6], c_[6];
    float4 sA, sB;
    #pragma unroll
    for (int ks = 0; ks < 6; ++ks) a_[ks] = *reinterpret_cast<const short8*>(pa + ks * 32);
    sA = *reinterpret_cast<const float4*>(sq + mbase + 4 * g);

    for (int it2 = 0; it2 < NIT / 2; ++it2){
        const int itA = it2 * 2, itB = itA + 1;
        {   // MFMA(A) -> prefetch B -> insert A
            f32x4 acc = {0.f, 0.f, 0.f, 0.f};
            #pragma unroll
            for (int ks = 0; ks < 6; ++ks)
                acc = __builtin_amdgcn_mfma_f32_16x16x32_bf16(a_[ks], bq[ks], acc, 0, 0, 0);
            const unsigned short* pn = pa + (size_t)itB * STP;
            #pragma unroll
            for (int ks = 0; ks < 6; ++ks) c_[ks] = *reinterpret_cast<const short8*>(pn + ks * 32);
            sB = *reinterpret_cast<const float4*>(sq + mbase + itB * 64 + 4 * g);
            knn_insert4(acc, sA, mbase + itA * 64 + 4 * g, Q, R);
        }
        {   // MFMA(B) -> prefetch A(+2) -> insert B
            f32x4 acc = {0.f, 0.f, 0.f, 0.f};
            #pragma unroll
            for (int ks = 0; ks < 6; ++ks)
                acc = __builtin_amdgcn_mfma_f32_16x16x32_bf16(c_[ks], bq[ks], acc, 0, 0, 0);
            const int itN = (itA + 2) & (NIT - 1);
            const unsigned short* pn = pa + (size_t)itN * STP;
            #pragma unroll
            for (int ks = 0; ks < 6; ++ks) a_[ks] = *reinterpret_cast<const short8*>(pn + ks * 32);
            sA = *reinterpret_cast<const float4*>(sq + mbase + itN * 64 + 4 * g);
            knn_insert4(acc, sB, mbase + itB * 64 + 4 * g, Q, R);
        }
    }

    // per-wave extraction: top-20 of Q ∪ R across the 4 g-lanes per query
    #pragma unroll 1
    for (int rd = 0; rd < KPH; ++rd){
        unsigned int lq = Q[0], lr = R[0];
        unsigned int lmin = umin_(lq, lr);
        unsigned int v = lmin;
        v = umin_(v, (unsigned int)__shfl_xor((int)v, 16));
        v = umin_(v, (unsigned int)__shfl_xor((int)v, 32));
        bool winq = (lq == v);
        bool winr = (lr == v) && !winq;
        if (winq){
            #pragma unroll
            for (int e = 0; e < 15; ++e) Q[e] = Q[e + 1];
            Q[15] = 0xFFFFFFFFu;
        } else if (winr){
            #pragma unroll
            for (int e = 0; e < 15; ++e) R[e] = R[e + 1];
            R[15] = 0xFFFFFFFFu;
        }
        if (g == 0) mlist[wv][r][rd] = v;
    }
    if (g == 0) mlist[wv][r][KPH] = 0xFFFFFFFFu;   // sentinel
    __syncthreads();

    // merge 4 sorted 20-lists per query -> top-20 indices for this half (keys unique)
    if (tid < 16){
        const int q = tid;
        int i0 = 0, i1 = 0, i2 = 0, i3 = 0;
        int* op = idxh + ((size_t)((size_t)(b * NPT + q0 + q) * 2 + half)) * KPH;
        for (int rd = 0; rd < KPH; ++rd){
            unsigned int k0 = mlist[0][q][i0], k1 = mlist[1][q][i1];
            unsigned int k2 = mlist[2][q][i2], k3 = mlist[3][q][i3];
            unsigned int mm = umin_(umin_(k0, k1), umin_(k2, k3));
            op[rd] = (int)(mm & 0xFFFu);
            i0 += (k0 == mm); i1 += (k1 == mm); i2 += (k2 == mm); i3 += (k3 == mm);
        }
    }
}

// ---------------- f64 re-rank of 40 candidates -> exact top-16 ----------------------------------
__global__ __launch_bounds__(64) void k_refine(
    const double* __restrict__ featT, const int* __restrict__ idxh, int* __restrict__ idxf)
{
    const int q = blockIdx.x, b = blockIdx.y, lane = threadIdx.x;
    const double* qv = featT + ((size_t)b * NPT + q) * CH;
    double q0 = qv[lane], q1 = qv[lane + 64], q2 = qv[lane + 128];
    double myd = INFINITY; int mym = 0x7fffffff;
    const int* cl = idxh + ((size_t)b * NPT + q) * KCAND;
    for (int t = 0; t < KCAND; ++t){
        int m = cl[t];
        const double* cv = featT + ((size_t)b * NPT + m) * CH;
        double d0 = cv[lane] - q0, d1 = cv[lane + 64] - q1, d2 = cv[lane + 128] - q2;
        double d = d0 * d0 + d1 * d1 + d2 * d2;
        #pragma unroll
        for (int off = 32; off; off >>= 1) d += __shfl_xor(d, off);
        if (lane == t){ myd = d; mym = m; }
    }
    for (int r = 0; r < KNB; ++r){
        double bv = myd; int bi = mym;
        #pragma unroll
        for (int off = 32; off; off >>= 1){
            double ov = __shfl_xor(bv, off);
            int    oi = __shfl_xor(bi, off);
            if (ov < bv || (ov == bv && oi < bi)){ bv = ov; bi = oi; }
        }
        if (lane == 0) idxf[((size_t)b * NPT + q) * KNB + r] = bi;
        if (mym == bi){ myd = INFINITY; mym = 0x7fffffff; }
    }
}

// ---------------- gather + BN0-apply + max-relative aggregate + channel interleave --------------
__global__ __launch_bounds__(256) void k_gather(
    const float* __restrict__ t1, const float* __restrict__ sc,
    const float* __restrict__ sh, const int* __restrict__ idx, float* __restrict__ hcat)
{
    __shared__ int il[KNB * 256];
    const int tid = threadIdx.x;
    const int n0  = blockIdx.x * 256;
    const int cg  = blockIdx.y;
    const int b   = blockIdx.z;
    for (int lin = tid; lin < 256 * KNB; lin += 256){
        int nl = lin >> 4, k = lin & 15;
        il[k * 256 + nl] = idx[((size_t)b * NPT + n0) * KNB + lin];
    }
    __syncthreads();
    const float* base = t1 + (size_t)b * CH * NPT;
    const int n = n0 + tid;
    for (int c = cg * 48; c < cg * 48 + 48; ++c){
        const float* row = base + (size_t)c * NPT;
        float s = sc[c], t = sh[c];
        float fi = fmaf(row[n], s, t);
        float mx = -INFINITY;
        #pragma unroll
        for (int k = 0; k < KNB; ++k){
            float v = fmaf(row[il[k * 256 + tid]], s, t);
            mx = fmaxf(mx, v - fi);
        }
        size_t o = ((size_t)b * 2 * CH + 2 * c) * NPT + n;
        hcat[o]       = fi;
        hcat[o + NPT] = mx;
    }
}

extern "C" void kernel_launch(void* const* d_in, const int* in_sizes, int n_in,
                              void* d_out, int out_size, void* d_ws, size_t ws_size,
                              hipStream_t stream)
{
    const float* x    = (const float*)d_in[0];
    const float* w1   = (const float*)d_in[1];
    const float* w2   = (const float*)d_in[2];
    const float* wmr  = (const float*)d_in[3];
    const float* bmr  = (const float*)d_in[4];
    const float* g0   = (const float*)d_in[5];
    const float* b0   = (const float*)d_in[6];
    const float* gm   = (const float*)d_in[7];
    const float* bm   = (const float*)d_in[8];
    const float* g1   = (const float*)d_in[9];
    const float* b1   = (const float*)d_in[10];
    float* outp = (float*)d_out;

    const size_t BCN = (size_t)BSZ * CH * NPT;
    float*  A     = (float*)d_ws;                       // BCN floats
    float*  Bb    = A + BCN;                            // BCN floats
    float*  Cc    = Bb + BCN;                           // 2*BCN floats
    double* t1d   = (double*)Cc;                        // BCN doubles (dead after k_tr64)
    unsigned short* featbf = (unsigned short*)Cc;       // BCN bf16 (alias; live knn only)
    double* featT = (double*)(Cc + 2 * BCN);            // BCN doubles
    float*  sqv   = (float*)(featT + BCN);              // B*N
    int*    idxh  = (int*)(sqv + (size_t)BSZ * NPT);    // B*N*40
    int*    idxf  = idxh + (size_t)BSZ * NPT * KCAND;   // B*N*16
    double* scd   = (double*)(idxf + (size_t)BSZ * NPT * KNB);
    float*  scb   = (float*)(scd + CH);
    float *sc0 = scb,          *sh0 = scb + CH;
    float *sc1 = scb + 2 * CH, *sh1 = scb + 3 * CH;
    float *sc2 = scb + 4 * CH, *sh2 = scb + 5 * CH;

    dim3 gg(NPT / 1024, CH / 8, BSZ);
    dim3 ge(NPT / 1024, CH, BSZ);

    // fc1 (f64 accumulate, dual fp32/f64 write)
    k_fc1_f64<<<gg, 256, 0, stream>>>(x, w1, A, t1d);
    // BN0 stats in f64
    k_stats_f64<<<CH, 256, 0, stream>>>(t1d, g0, b0, sc0, sh0, scd);
    // f64 scaled (shift-free) transposed features
    k_tr64<<<dim3(NPT / 32, CH / 32, BSZ), dim3(32, 8), 0, stream>>>(t1d, scd, featT);
    // bf16 features + fp32 sq norms (t1d dead; featbf overwrites it)
    k_bf_sq<<<dim3(NPT / 4, BSZ), 256, 0, stream>>>(featT, featbf, sqv);
    // kNN: MFMA bf16 prefilter (2 halves x top-20) -> f64 exact top-16
    k_knn_mfma<<<dim3(2 * NPT / 16, BSZ), 256, 0, stream>>>(featbf, sqv, idxh);
    k_refine<<<dim3(NPT, BSZ), 64, 0, stream>>>(featT, idxh, idxf);
    // gather with BN0 folded in (reads pre-BN t1) + aggregate + interleave
    k_gather<<<dim3(NPT / 256, 4, BSZ), 256, 0, stream>>>(A, sc0, sh0, idxf, Cc);
    // mr conv (K=384) + bias
    k_gemm<2 * CH, true, false, false><<<gg, 256, 0, stream>>>(Cc, wmr, bmr, nullptr, nullptr, nullptr, A);
    // BN1 stats, u = gelu(gelu(BN1(t2)))
    k_stats<<<CH, 256, 0, stream>>>(A, gm, bm, sc1, sh1);
    k_u<<<ge, 256, 0, stream>>>(A, sc1, sh1, Bb);
    // BN2 stats, fc2 with BN folded into input + residual
    k_stats<<<CH, 256, 0, stream>>>(Bb, g1, b1, sc2, sh2);
    k_gemm<CH, false, true, true><<<gg, 256, 0, stream>>>(Bb, w2, nullptr, sc2, sh2, x, outp);
}

// Round 7
// 628.037 us; speedup vs baseline: 1.0194x; 1.0194x over previous
//
#include <hip/hip_runtime.h>
#include <hip/hip_bf16.h>
#include <math.h>

#define BSZ 4
#define CH  192
#define NPT 4096
#define KNB 16
#define KPH 20              // kept per half
#define KCAND (2 * KPH)     // refine candidates

typedef short short8 __attribute__((ext_vector_type(8)));
typedef float f32x4  __attribute__((ext_vector_type(4)));

__device__ __forceinline__ float gelu_exact(float x){
    return 0.5f * x * (1.0f + erff(x * 0.70710678118654752440f));
}
__device__ __forceinline__ unsigned int umin_(unsigned int a, unsigned int b){ return a < b ? a : b; }
__device__ __forceinline__ unsigned int umax_(unsigned int a, unsigned int b){ return a < b ? b : a; }

// ---------------- fp32 GEMM: out[b,o,n] = sum_c W[o,c] * in[b,c,n] (+bias)(+BN-fold)(+resid) ----
template<int KDIM, bool BIASED, bool SCALED, bool RESID>
__global__ __launch_bounds__(256) void k_gemm(
    const float* __restrict__ in, const float* __restrict__ W,
    const float* __restrict__ bias, const float* __restrict__ sc,
    const float* __restrict__ sh, const float* __restrict__ resid,
    float* __restrict__ out)
{
    constexpr int OT = 8, NT = 4;
    __shared__ float wtT[KDIM][OT];
    __shared__ float scl[SCALED ? KDIM : 1];
    __shared__ float shl[SCALED ? KDIM : 1];
    const int tid = threadIdx.x;
    const int o0  = blockIdx.y * OT;
    const int b   = blockIdx.z;
    const int n   = blockIdx.x * (256 * NT) + tid * NT;

    for (int lin = tid; lin < KDIM * OT; lin += 256){
        int c = lin >> 3, o = lin & 7;
        wtT[c][o] = W[(size_t)(o0 + o) * KDIM + c];
    }
    if (SCALED){
        for (int c = tid; c < KDIM; c += 256){ scl[c] = sc[c]; shl[c] = sh[c]; }
    }
    __syncthreads();

    float acc[OT][NT] = {};
    const float* ip = in + (size_t)b * KDIM * NPT + n;
    #pragma unroll 2
    for (int c = 0; c < KDIM; ++c){
        float4 x4 = *reinterpret_cast<const float4*>(ip + (size_t)c * NPT);
        float xv[NT] = {x4.x, x4.y, x4.z, x4.w};
        if (SCALED){
            #pragma unroll
            for (int j = 0; j < NT; ++j) xv[j] = fmaf(xv[j], scl[c], shl[c]);
        }
        float4 w0 = *reinterpret_cast<const float4*>(&wtT[c][0]);
        float4 w1 = *reinterpret_cast<const float4*>(&wtT[c][4]);
        float wv[OT] = {w0.x, w0.y, w0.z, w0.w, w1.x, w1.y, w1.z, w1.w};
        #pragma unroll
        for (int oo = 0; oo < OT; ++oo)
            #pragma unroll
            for (int j = 0; j < NT; ++j)
                acc[oo][j] = fmaf(wv[oo], xv[j], acc[oo][j]);
    }

    #pragma unroll
    for (int oo = 0; oo < OT; ++oo){
        size_t off = ((size_t)b * CH + o0 + oo) * NPT + n;
        float add = BIASED ? bias[o0 + oo] : 0.0f;
        float vals[4];
        #pragma unroll
        for (int j = 0; j < 4; ++j) vals[j] = acc[oo][j] + add;
        if (RESID){
            float4 r4 = *reinterpret_cast<const float4*>(resid + off);
            vals[0] += r4.x; vals[1] += r4.y; vals[2] += r4.z; vals[3] += r4.w;
        }
        float4 o4; o4.x = vals[0]; o4.y = vals[1]; o4.z = vals[2]; o4.w = vals[3];
        *reinterpret_cast<float4*>(out + off) = o4;
    }
}

// ---------------- fc1 with f64 accumulation: writes fp32 t1 and f64 t1 --------------------------
__global__ __launch_bounds__(256) void k_fc1_f64(
    const float* __restrict__ in, const float* __restrict__ W,
    float* __restrict__ outf, double* __restrict__ outd)
{
    constexpr int OT = 8, NT = 4;
    __shared__ float wtT[CH][OT];
    const int tid = threadIdx.x;
    const int o0  = blockIdx.y * OT;
    const int b   = blockIdx.z;
    const int n   = blockIdx.x * (256 * NT) + tid * NT;

    for (int lin = tid; lin < CH * OT; lin += 256){
        int c = lin >> 3, o = lin & 7;
        wtT[c][o] = W[(size_t)(o0 + o) * CH + c];
    }
    __syncthreads();

    double acc[OT][NT] = {};
    const float* ip = in + (size_t)b * CH * NPT + n;
    for (int c = 0; c < CH; ++c){
        float4 x4 = *reinterpret_cast<const float4*>(ip + (size_t)c * NPT);
        double xv[NT] = {x4.x, x4.y, x4.z, x4.w};
        float4 w0 = *reinterpret_cast<const float4*>(&wtT[c][0]);
        float4 w1 = *reinterpret_cast<const float4*>(&wtT[c][4]);
        double wv[OT] = {w0.x, w0.y, w0.z, w0.w, w1.x, w1.y, w1.z, w1.w};
        #pragma unroll
        for (int oo = 0; oo < OT; ++oo)
            #pragma unroll
            for (int j = 0; j < NT; ++j)
                acc[oo][j] = fma(wv[oo], xv[j], acc[oo][j]);
    }

    #pragma unroll
    for (int oo = 0; oo < OT; ++oo){
        size_t off = ((size_t)b * CH + o0 + oo) * NPT + n;
        #pragma unroll
        for (int j = 0; j < 4; ++j){
            outf[off + j] = (float)acc[oo][j];
            outd[off + j] = acc[oo][j];
        }
    }
}

// ---------------- f64 BN0 stats: fp32 scale/shift + f64 scale for kNN ---------------------------
__global__ __launch_bounds__(256) void k_stats_f64(
    const double* __restrict__ t, const float* __restrict__ gamma,
    const float* __restrict__ beta, float* __restrict__ scale,
    float* __restrict__ shift, double* __restrict__ scd)
{
    const int c = blockIdx.x, tid = threadIdx.x;
    double s = 0., s2 = 0.;
    for (int b = 0; b < BSZ; ++b){
        const double* p = t + ((size_t)b * CH + c) * NPT;
        for (int n = tid; n < NPT; n += 256){ double v = p[n]; s += v; s2 += v * v; }
    }
    __shared__ double rs[256], rs2[256];
    rs[tid] = s; rs2[tid] = s2; __syncthreads();
    for (int off = 128; off; off >>= 1){
        if (tid < off){ rs[tid] += rs[tid + off]; rs2[tid] += rs2[tid + off]; }
        __syncthreads();
    }
    if (tid == 0){
        const double invn = 1.0 / (BSZ * NPT);
        double mean = rs[0] * invn;
        double var  = rs2[0] * invn - mean * mean;
        double rstd = 1.0 / sqrt(var + 1e-5);
        double s_   = rstd * (double)gamma[c];
        scale[c] = (float)s_;
        shift[c] = (float)((double)beta[c] - mean * s_);
        scd[c]   = s_;
    }
}

// ---------------- fp32 per-channel batch stats -> scale/shift -----------------------------------
__global__ __launch_bounds__(256) void k_stats(
    const float* __restrict__ t, const float* __restrict__ gamma,
    const float* __restrict__ beta, float* __restrict__ scale, float* __restrict__ shift)
{
    const int c = blockIdx.x, tid = threadIdx.x;
    float s = 0.f, s2 = 0.f;
    for (int b = 0; b < BSZ; ++b){
        const float* p = t + ((size_t)b * CH + c) * NPT;
        for (int n = tid; n < NPT; n += 256){ float v = p[n]; s += v; s2 += v * v; }
    }
    __shared__ float rs[256], rs2[256];
    rs[tid] = s; rs2[tid] = s2; __syncthreads();
    for (int off = 128; off; off >>= 1){
        if (tid < off){ rs[tid] += rs[tid + off]; rs2[tid] += rs2[tid + off]; }
        __syncthreads();
    }
    if (tid == 0){
        const float invn = 1.0f / (BSZ * NPT);
        float mean = rs[0] * invn;
        float var  = rs2[0] * invn - mean * mean;
        float rstd = rsqrtf(var + 1e-5f);
        float s_   = rstd * gamma[c];
        scale[c] = s_;
        shift[c] = beta[c] - mean * s_;
    }
}

// ---------------- transpose + per-channel f64 scale: featT[b][n][c] -----------------------------
__global__ void k_tr64(const double* __restrict__ t1d, const double* __restrict__ scd,
                       double* __restrict__ featT)
{
    __shared__ double tile[32][33];
    const int n0 = blockIdx.x * 32, c0 = blockIdx.y * 32, b = blockIdx.z;
    #pragma unroll
    for (int r = 0; r < 32; r += 8){
        int c = c0 + threadIdx.y + r, n = n0 + threadIdx.x;
        tile[threadIdx.y + r][threadIdx.x] = t1d[((size_t)b * CH + c) * NPT + n] * scd[c];
    }
    __syncthreads();
    #pragma unroll
    for (int r = 0; r < 32; r += 8){
        int n = n0 + threadIdx.y + r, c = c0 + threadIdx.x;
        featT[((size_t)b * NPT + n) * CH + c] = tile[threadIdx.x][threadIdx.y + r];
    }
}

// ---------------- featT (f64, shift-free) -> bf16 features + fp32 sq norms ----------------------
__global__ __launch_bounds__(256) void k_bf_sq(
    const double* __restrict__ featT, unsigned short* __restrict__ featbf,
    float* __restrict__ sqv)
{
    const int wid  = threadIdx.x >> 6;
    const int lane = threadIdx.x & 63;
    const int row  = blockIdx.x * 4 + wid;
    const int b    = blockIdx.y;
    const double* p = featT + ((size_t)b * NPT + row) * CH;
    unsigned short* o = featbf + ((size_t)b * NPT + row) * CH;
    float s = 0.f;
    #pragma unroll
    for (int j = 0; j < 3; ++j){
        float v = (float)p[lane + 64 * j];
        s = fmaf(v, v, s);
        unsigned int bits = __builtin_bit_cast(unsigned int, v);
        o[lane + 64 * j] = (unsigned short)((bits + 0x7fff + ((bits >> 16) & 1)) >> 16);
    }
    #pragma unroll
    for (int off = 32; off; off >>= 1) s += __shfl_xor(s, off);
    if (lane == 0) sqv[b * NPT + row] = s;
}

// ---------------- double-GELU(BN) ----------------------------------------------------------------
__global__ __launch_bounds__(256) void k_u(
    const float* __restrict__ in, const float* __restrict__ sc,
    const float* __restrict__ sh, float* __restrict__ out)
{
    const int c = blockIdx.y, b = blockIdx.z;
    const int n = (blockIdx.x * 256 + threadIdx.x) * 4;
    size_t i = ((size_t)b * CH + c) * NPT + n;
    float4 v = *reinterpret_cast<const float4*>(in + i);
    float s = sc[c], t = sh[c];
    float4 o;
    o.x = gelu_exact(gelu_exact(fmaf(v.x, s, t)));
    o.y = gelu_exact(gelu_exact(fmaf(v.y, s, t)));
    o.z = gelu_exact(gelu_exact(fmaf(v.z, s, t)));
    o.w = gelu_exact(gelu_exact(fmaf(v.w, s, t)));
    *reinterpret_cast<float4*>(out + i) = o;
}

// ---------------- MFMA kNN prefilter v5 -----------------------------------------------------------
// grid (NPT/32 * 2, BSZ): 128 q-tiles (32 q) x 2 m-halves. 4 waves/block:
// wave w: q-sub w>>1 (16 q), m-quarter w&1 (1024 m in 16-m tiles, 64 iters).
// No explicit staging pipeline (TLP hides latency). Dual 16-deep packed-key lists per lane.
// key = sortable-u32(distance) top 20 bits | index (12 bits); globally unique.
__global__ __launch_bounds__(256) void k_knn_mfma(
    const unsigned short* __restrict__ featbf, const float* __restrict__ sqv,
    int* __restrict__ idxh)
{
    __shared__ unsigned int mlist[4][16][17];
    const int tid  = threadIdx.x;
    const int wv   = tid >> 6;
    const int lane = tid & 63;
    const int r = lane & 15, g = lane >> 4;
    const int b    = blockIdx.y;
    const int qt   = blockIdx.x >> 1;
    const int half = blockIdx.x & 1;
    const int q0   = qt * 32 + (wv >> 1) * 16;
    const int mbase = half * 2048 + (wv & 1) * 1024;
    const unsigned short* fb = featbf + (size_t)b * NPT * CH;

    short8 bq[6];
    {
        const unsigned short* qp = fb + (size_t)(q0 + r) * CH + g * 8;
        #pragma unroll
        for (int ks = 0; ks < 6; ++ks) bq[ks] = *reinterpret_cast<const short8*>(qp + ks * 32);
    }

    unsigned int Q[16], R[16];
    #pragma unroll
    for (int e = 0; e < 16; ++e){ Q[e] = 0xFFFFFFFFu; R[e] = 0xFFFFFFFFu; }

    const float* sq = sqv + b * NPT;
    const unsigned short* pa = fb + (size_t)(mbase + r) * CH + g * 8;

    for (int it = 0; it < 64; ++it){
        const unsigned short* p = pa + (size_t)it * (16 * CH);
        short8 a0 = *reinterpret_cast<const short8*>(p);
        short8 a1 = *reinterpret_cast<const short8*>(p + 32);
        short8 a2 = *reinterpret_cast<const short8*>(p + 64);
        short8 a3 = *reinterpret_cast<const short8*>(p + 96);
        short8 a4 = *reinterpret_cast<const short8*>(p + 128);
        short8 a5 = *reinterpret_cast<const short8*>(p + 160);
        float4 s4 = *reinterpret_cast<const float4*>(sq + mbase + it * 16 + 4 * g);

        f32x4 acc = {0.f, 0.f, 0.f, 0.f};
        acc = __builtin_amdgcn_mfma_f32_16x16x32_bf16(a0, bq[0], acc, 0, 0, 0);
        acc = __builtin_amdgcn_mfma_f32_16x16x32_bf16(a1, bq[1], acc, 0, 0, 0);
        acc = __builtin_amdgcn_mfma_f32_16x16x32_bf16(a2, bq[2], acc, 0, 0, 0);
        acc = __builtin_amdgcn_mfma_f32_16x16x32_bf16(a3, bq[3], acc, 0, 0, 0);
        acc = __builtin_amdgcn_mfma_f32_16x16x32_bf16(a4, bq[4], acc, 0, 0, 0);
        acc = __builtin_amdgcn_mfma_f32_16x16x32_bf16(a5, bq[5], acc, 0, 0, 0);

        const int m0 = mbase + it * 16 + 4 * g;
        float sa[4] = {s4.x, s4.y, s4.z, s4.w};
        #pragma unroll
        for (int u = 0; u < 4; ++u){
            float d = fmaf(-2.0f, acc[u], sa[u]);
            int bb = __builtin_bit_cast(int, d);
            unsigned int uu = (unsigned int)(bb ^ ((bb >> 31) | 0x80000000));
            unsigned int k  = (uu & 0xFFFFF000u) | (unsigned int)(m0 + u);
            if (u & 1){
                #pragma unroll
                for (int e = 0; e < 16; ++e){
                    unsigned int qe = R[e]; R[e] = umin_(k, qe); k = umax_(k, qe);
                }
            } else {
                #pragma unroll
                for (int e = 0; e < 16; ++e){
                    unsigned int qe = Q[e]; Q[e] = umin_(k, qe); k = umax_(k, qe);
                }
            }
        }
    }

    // per-wave extraction: top-16 of Q ∪ R across the 4 g-lanes per query
    #pragma unroll 1
    for (int rd = 0; rd < 16; ++rd){
        unsigned int lq = Q[0], lr = R[0];
        unsigned int v = umin_(lq, lr);
        v = umin_(v, (unsigned int)__shfl_xor((int)v, 16));
        v = umin_(v, (unsigned int)__shfl_xor((int)v, 32));
        bool winq = (lq == v);
        bool winr = (lr == v) && !winq;
        if (winq){
            #pragma unroll
            for (int e = 0; e < 15; ++e) Q[e] = Q[e + 1];
            Q[15] = 0xFFFFFFFFu;
        } else if (winr){
            #pragma unroll
            for (int e = 0; e < 15; ++e) R[e] = R[e + 1];
            R[15] = 0xFFFFFFFFu;
        }
        if (g == 0) mlist[wv][r][rd] = v;
    }
    if (g == 0) mlist[wv][r][16] = 0xFFFFFFFFu;   // sentinel
    __syncthreads();

    // merge the 2 m-quarter lists per query -> top-20 for this half (keys unique)
    if (tid < 32){
        const int qq = tid;            // query within block (0..31)
        const int qs = qq >> 4, rr = qq & 15;
        int i0 = 0, i1 = 0;
        int* op = idxh + ((size_t)(b * NPT + qt * 32 + qq) * 2 + half) * KPH;
        for (int rd = 0; rd < KPH; ++rd){
            unsigned int k0 = mlist[qs * 2][rr][i0];
            unsigned int k1 = mlist[qs * 2 + 1][rr][i1];
            unsigned int mm = umin_(k0, k1);
            op[rd] = (int)(mm & 0xFFFu);
            i0 += (k0 == mm); i1 += (k1 == mm);
        }
    }
}

// ---------------- f64 re-rank of 40 candidates -> exact top-16 ----------------------------------
__global__ __launch_bounds__(64) void k_refine(
    const double* __restrict__ featT, const int* __restrict__ idxh, int* __restrict__ idxf)
{
    const int q = blockIdx.x, b = blockIdx.y, lane = threadIdx.x;
    const double* qv = featT + ((size_t)b * NPT + q) * CH;
    double q0 = qv[lane], q1 = qv[lane + 64], q2 = qv[lane + 128];
    double myd = INFINITY; int mym = 0x7fffffff;
    const int* cl = idxh + ((size_t)b * NPT + q) * KCAND;
    for (int t = 0; t < KCAND; ++t){
        int m = cl[t];
        const double* cv = featT + ((size_t)b * NPT + m) * CH;
        double d0 = cv[lane] - q0, d1 = cv[lane + 64] - q1, d2 = cv[lane + 128] - q2;
        double d = d0 * d0 + d1 * d1 + d2 * d2;
        #pragma unroll
        for (int off = 32; off; off >>= 1) d += __shfl_xor(d, off);
        if (lane == t){ myd = d; mym = m; }
    }
    for (int r = 0; r < KNB; ++r){
        double bv = myd; int bi = mym;
        #pragma unroll
        for (int off = 32; off; off >>= 1){
            double ov = __shfl_xor(bv, off);
            int    oi = __shfl_xor(bi, off);
            if (ov < bv || (ov == bv && oi < bi)){ bv = ov; bi = oi; }
        }
        if (lane == 0) idxf[((size_t)b * NPT + q) * KNB + r] = bi;
        if (mym == bi){ myd = INFINITY; mym = 0x7fffffff; }
    }
}

// ---------------- gather + BN0-apply + max-relative aggregate + channel interleave --------------
__global__ __launch_bounds__(256) void k_gather(
    const float* __restrict__ t1, const float* __restrict__ sc,
    const float* __restrict__ sh, const int* __restrict__ idx, float* __restrict__ hcat)
{
    __shared__ int il[KNB * 256];
    const int tid = threadIdx.x;
    const int n0  = blockIdx.x * 256;
    const int cg  = blockIdx.y;
    const int b   = blockIdx.z;
    for (int lin = tid; lin < 256 * KNB; lin += 256){
        int nl = lin >> 4, k = lin & 15;
        il[k * 256 + nl] = idx[((size_t)b * NPT + n0) * KNB + lin];
    }
    __syncthreads();
    const float* base = t1 + (size_t)b * CH * NPT;
    const int n = n0 + tid;
    for (int c = cg * 48; c < cg * 48 + 48; ++c){
        const float* row = base + (size_t)c * NPT;
        float s = sc[c], t = sh[c];
        float fi = fmaf(row[n], s, t);
        float mx = -INFINITY;
        #pragma unroll
        for (int k = 0; k < KNB; ++k){
            float v = fmaf(row[il[k * 256 + tid]], s, t);
            mx = fmaxf(mx, v - fi);
        }
        size_t o = ((size_t)b * 2 * CH + 2 * c) * NPT + n;
        hcat[o]       = fi;
        hcat[o + NPT] = mx;
    }
}

extern "C" void kernel_launch(void* const* d_in, const int* in_sizes, int n_in,
                              void* d_out, int out_size, void* d_ws, size_t ws_size,
                              hipStream_t stream)
{
    const float* x    = (const float*)d_in[0];
    const float* w1   = (const float*)d_in[1];
    const float* w2   = (const float*)d_in[2];
    const float* wmr  = (const float*)d_in[3];
    const float* bmr  = (const float*)d_in[4];
    const float* g0   = (const float*)d_in[5];
    const float* b0   = (const float*)d_in[6];
    const float* gm   = (const float*)d_in[7];
    const float* bm   = (const float*)d_in[8];
    const float* g1   = (const float*)d_in[9];
    const float* b1   = (const float*)d_in[10];
    float* outp = (float*)d_out;

    const size_t BCN = (size_t)BSZ * CH * NPT;
    float*  A     = (float*)d_ws;                       // BCN floats
    float*  Bb    = A + BCN;                            // BCN floats
    float*  Cc    = Bb + BCN;                           // 2*BCN floats
    double* t1d   = (double*)Cc;                        // BCN doubles (dead after k_tr64)
    unsigned short* featbf = (unsigned short*)Cc;       // BCN bf16 (alias; live knn only)
    double* featT = (double*)(Cc + 2 * BCN);            // BCN doubles
    float*  sqv   = (float*)(featT + BCN);              // B*N
    int*    idxh  = (int*)(sqv + (size_t)BSZ * NPT);    // B*N*40
    int*    idxf  = idxh + (size_t)BSZ * NPT * KCAND;   // B*N*16
    double* scd   = (double*)(idxf + (size_t)BSZ * NPT * KNB);
    float*  scb   = (float*)(scd + CH);
    float *sc0 = scb,          *sh0 = scb + CH;
    float *sc1 = scb + 2 * CH, *sh1 = scb + 3 * CH;
    float *sc2 = scb + 4 * CH, *sh2 = scb + 5 * CH;

    dim3 gg(NPT / 1024, CH / 8, BSZ);
    dim3 ge(NPT / 1024, CH, BSZ);

    // fc1 (f64 accumulate, dual fp32/f64 write)
    k_fc1_f64<<<gg, 256, 0, stream>>>(x, w1, A, t1d);
    // BN0 stats in f64
    k_stats_f64<<<CH, 256, 0, stream>>>(t1d, g0, b0, sc0, sh0, scd);
    // f64 scaled (shift-free) transposed features
    k_tr64<<<dim3(NPT / 32, CH / 32, BSZ), dim3(32, 8), 0, stream>>>(t1d, scd, featT);
    // bf16 features + fp32 sq norms (t1d dead; featbf overwrites it)
    k_bf_sq<<<dim3(NPT / 4, BSZ), 256, 0, stream>>>(featT, featbf, sqv);
    // kNN: MFMA bf16 prefilter (q-tile 32, 2 halves x top-20) -> f64 exact top-16
    k_knn_mfma<<<dim3(2 * NPT / 32, BSZ), 256, 0, stream>>>(featbf, sqv, idxh);
    k_refine<<<dim3(NPT, BSZ), 64, 0, stream>>>(featT, idxh, idxf);
    // gather with BN0 folded in (reads pre-BN t1) + aggregate + interleave
    k_gather<<<dim3(NPT / 256, 4, BSZ), 256, 0, stream>>>(A, sc0, sh0, idxf, Cc);
    // mr conv (K=384) + bias
    k_gemm<2 * CH, true, false, false><<<gg, 256, 0, stream>>>(Cc, wmr, bmr, nullptr, nullptr, nullptr, A);
    // BN1 stats, u = gelu(gelu(BN1(t2)))
    k_stats<<<CH, 256, 0, stream>>>(A, gm, bm, sc1, sh1);
    k_u<<<ge, 256, 0, stream>>>(A, sc1, sh1, Bb);
    // BN2 stats, fc2 with BN folded into input + residual
    k_stats<<<CH, 256, 0, stream>>>(Bb, g1, b1, sc2, sh2);
    k_gemm<CH, false, true, true><<<gg, 256, 0, stream>>>(Bb, w2, nullptr, sc2, sh2, x, outp);
}

// Round 8
// 626.087 us; speedup vs baseline: 1.0225x; 1.0031x over previous
//
#include <hip/hip_runtime.h>
#include <hip/hip_bf16.h>
#include <math.h>

#define BSZ 4
#define CH  192
#define NPT 4096
#define KNB 16
#define KPH 20              // kept per half
#define KCAND (2 * KPH)     // refine candidates

typedef short short8 __attribute__((ext_vector_type(8)));
typedef float f32x4  __attribute__((ext_vector_type(4)));

__device__ __forceinline__ float gelu_exact(float x){
    return 0.5f * x * (1.0f + erff(x * 0.70710678118654752440f));
}
__device__ __forceinline__ unsigned int umin_(unsigned int a, unsigned int b){ return a < b ? a : b; }
__device__ __forceinline__ unsigned int umax_(unsigned int a, unsigned int b){ return a < b ? b : a; }
__device__ __forceinline__ unsigned int umed3_(unsigned int a, unsigned int b, unsigned int c){
    unsigned int r;
    asm("v_med3_u32 %0, %1, %2, %3" : "=v"(r) : "v"(a), "v"(b), "v"(c));
    return r;
}

// ---------------- fp32 GEMM: out[b,o,n] = sum_c W[o,c] * in[b,c,n] (+bias)(+BN-fold)(+resid) ----
template<int KDIM, bool BIASED, bool SCALED, bool RESID>
__global__ __launch_bounds__(256) void k_gemm(
    const float* __restrict__ in, const float* __restrict__ W,
    const float* __restrict__ bias, const float* __restrict__ sc,
    const float* __restrict__ sh, const float* __restrict__ resid,
    float* __restrict__ out)
{
    constexpr int OT = 8, NT = 4;
    __shared__ float wtT[KDIM][OT];
    __shared__ float scl[SCALED ? KDIM : 1];
    __shared__ float shl[SCALED ? KDIM : 1];
    const int tid = threadIdx.x;
    const int o0  = blockIdx.y * OT;
    const int b   = blockIdx.z;
    const int n   = blockIdx.x * (256 * NT) + tid * NT;

    for (int lin = tid; lin < KDIM * OT; lin += 256){
        int c = lin >> 3, o = lin & 7;
        wtT[c][o] = W[(size_t)(o0 + o) * KDIM + c];
    }
    if (SCALED){
        for (int c = tid; c < KDIM; c += 256){ scl[c] = sc[c]; shl[c] = sh[c]; }
    }
    __syncthreads();

    float acc[OT][NT] = {};
    const float* ip = in + (size_t)b * KDIM * NPT + n;
    #pragma unroll 2
    for (int c = 0; c < KDIM; ++c){
        float4 x4 = *reinterpret_cast<const float4*>(ip + (size_t)c * NPT);
        float xv[NT] = {x4.x, x4.y, x4.z, x4.w};
        if (SCALED){
            #pragma unroll
            for (int j = 0; j < NT; ++j) xv[j] = fmaf(xv[j], scl[c], shl[c]);
        }
        float4 w0 = *reinterpret_cast<const float4*>(&wtT[c][0]);
        float4 w1 = *reinterpret_cast<const float4*>(&wtT[c][4]);
        float wv[OT] = {w0.x, w0.y, w0.z, w0.w, w1.x, w1.y, w1.z, w1.w};
        #pragma unroll
        for (int oo = 0; oo < OT; ++oo)
            #pragma unroll
            for (int j = 0; j < NT; ++j)
                acc[oo][j] = fmaf(wv[oo], xv[j], acc[oo][j]);
    }

    #pragma unroll
    for (int oo = 0; oo < OT; ++oo){
        size_t off = ((size_t)b * CH + o0 + oo) * NPT + n;
        float add = BIASED ? bias[o0 + oo] : 0.0f;
        float vals[4];
        #pragma unroll
        for (int j = 0; j < 4; ++j) vals[j] = acc[oo][j] + add;
        if (RESID){
            float4 r4 = *reinterpret_cast<const float4*>(resid + off);
            vals[0] += r4.x; vals[1] += r4.y; vals[2] += r4.z; vals[3] += r4.w;
        }
        float4 o4; o4.x = vals[0]; o4.y = vals[1]; o4.z = vals[2]; o4.w = vals[3];
        *reinterpret_cast<float4*>(out + off) = o4;
    }
}

// ---------------- fc1 with f64 accumulation: writes fp32 t1 and f64 t1 --------------------------
__global__ __launch_bounds__(256) void k_fc1_f64(
    const float* __restrict__ in, const float* __restrict__ W,
    float* __restrict__ outf, double* __restrict__ outd)
{
    constexpr int OT = 8, NT = 4;
    __shared__ float wtT[CH][OT];
    const int tid = threadIdx.x;
    const int o0  = blockIdx.y * OT;
    const int b   = blockIdx.z;
    const int n   = blockIdx.x * (256 * NT) + tid * NT;

    for (int lin = tid; lin < CH * OT; lin += 256){
        int c = lin >> 3, o = lin & 7;
        wtT[c][o] = W[(size_t)(o0 + o) * CH + c];
    }
    __syncthreads();

    double acc[OT][NT] = {};
    const float* ip = in + (size_t)b * CH * NPT + n;
    for (int c = 0; c < CH; ++c){
        float4 x4 = *reinterpret_cast<const float4*>(ip + (size_t)c * NPT);
        double xv[NT] = {x4.x, x4.y, x4.z, x4.w};
        float4 w0 = *reinterpret_cast<const float4*>(&wtT[c][0]);
        float4 w1 = *reinterpret_cast<const float4*>(&wtT[c][4]);
        double wv[OT] = {w0.x, w0.y, w0.z, w0.w, w1.x, w1.y, w1.z, w1.w};
        #pragma unroll
        for (int oo = 0; oo < OT; ++oo)
            #pragma unroll
            for (int j = 0; j < NT; ++j)
                acc[oo][j] = fma(wv[oo], xv[j], acc[oo][j]);
    }

    #pragma unroll
    for (int oo = 0; oo < OT; ++oo){
        size_t off = ((size_t)b * CH + o0 + oo) * NPT + n;
        #pragma unroll
        for (int j = 0; j < 4; ++j){
            outf[off + j] = (float)acc[oo][j];
            outd[off + j] = acc[oo][j];
        }
    }
}

// ---------------- f64 BN0 stats: fp32 scale/shift + f64 scale for kNN ---------------------------
__global__ __launch_bounds__(256) void k_stats_f64(
    const double* __restrict__ t, const float* __restrict__ gamma,
    const float* __restrict__ beta, float* __restrict__ scale,
    float* __restrict__ shift, double* __restrict__ scd)
{
    const int c = blockIdx.x, tid = threadIdx.x;
    double s = 0., s2 = 0.;
    for (int b = 0; b < BSZ; ++b){
        const double* p = t + ((size_t)b * CH + c) * NPT;
        for (int n = tid; n < NPT; n += 256){ double v = p[n]; s += v; s2 += v * v; }
    }
    __shared__ double rs[256], rs2[256];
    rs[tid] = s; rs2[tid] = s2; __syncthreads();
    for (int off = 128; off; off >>= 1){
        if (tid < off){ rs[tid] += rs[tid + off]; rs2[tid] += rs2[tid + off]; }
        __syncthreads();
    }
    if (tid == 0){
        const double invn = 1.0 / (BSZ * NPT);
        double mean = rs[0] * invn;
        double var  = rs2[0] * invn - mean * mean;
        double rstd = 1.0 / sqrt(var + 1e-5);
        double s_   = rstd * (double)gamma[c];
        scale[c] = (float)s_;
        shift[c] = (float)((double)beta[c] - mean * s_);
        scd[c]   = s_;
    }
}

// ---------------- fp32 per-channel batch stats -> scale/shift -----------------------------------
__global__ __launch_bounds__(256) void k_stats(
    const float* __restrict__ t, const float* __restrict__ gamma,
    const float* __restrict__ beta, float* __restrict__ scale, float* __restrict__ shift)
{
    const int c = blockIdx.x, tid = threadIdx.x;
    float s = 0.f, s2 = 0.f;
    for (int b = 0; b < BSZ; ++b){
        const float* p = t + ((size_t)b * CH + c) * NPT;
        for (int n = tid; n < NPT; n += 256){ float v = p[n]; s += v; s2 += v * v; }
    }
    __shared__ float rs[256], rs2[256];
    rs[tid] = s; rs2[tid] = s2; __syncthreads();
    for (int off = 128; off; off >>= 1){
        if (tid < off){ rs[tid] += rs[tid + off]; rs2[tid] += rs2[tid + off]; }
        __syncthreads();
    }
    if (tid == 0){
        const float invn = 1.0f / (BSZ * NPT);
        float mean = rs[0] * invn;
        float var  = rs2[0] * invn - mean * mean;
        float rstd = rsqrtf(var + 1e-5f);
        float s_   = rstd * gamma[c];
        scale[c] = s_;
        shift[c] = beta[c] - mean * s_;
    }
}

// ---------------- transpose + per-channel f64 scale: featT[b][n][c] -----------------------------
__global__ void k_tr64(const double* __restrict__ t1d, const double* __restrict__ scd,
                       double* __restrict__ featT)
{
    __shared__ double tile[32][33];
    const int n0 = blockIdx.x * 32, c0 = blockIdx.y * 32, b = blockIdx.z;
    #pragma unroll
    for (int r = 0; r < 32; r += 8){
        int c = c0 + threadIdx.y + r, n = n0 + threadIdx.x;
        tile[threadIdx.y + r][threadIdx.x] = t1d[((size_t)b * CH + c) * NPT + n] * scd[c];
    }
    __syncthreads();
    #pragma unroll
    for (int r = 0; r < 32; r += 8){
        int n = n0 + threadIdx.y + r, c = c0 + threadIdx.x;
        featT[((size_t)b * NPT + n) * CH + c] = tile[threadIdx.x][threadIdx.y + r];
    }
}

// ---------------- featT (f64, shift-free) -> bf16 features + fp32 sq norms ----------------------
__global__ __launch_bounds__(256) void k_bf_sq(
    const double* __restrict__ featT, unsigned short* __restrict__ featbf,
    float* __restrict__ sqv)
{
    const int wid  = threadIdx.x >> 6;
    const int lane = threadIdx.x & 63;
    const int row  = blockIdx.x * 4 + wid;
    const int b    = blockIdx.y;
    const double* p = featT + ((size_t)b * NPT + row) * CH;
    unsigned short* o = featbf + ((size_t)b * NPT + row) * CH;
    float s = 0.f;
    #pragma unroll
    for (int j = 0; j < 3; ++j){
        float v = (float)p[lane + 64 * j];
        s = fmaf(v, v, s);
        unsigned int bits = __builtin_bit_cast(unsigned int, v);
        o[lane + 64 * j] = (unsigned short)((bits + 0x7fff + ((bits >> 16) & 1)) >> 16);
    }
    #pragma unroll
    for (int off = 32; off; off >>= 1) s += __shfl_xor(s, off);
    if (lane == 0) sqv[b * NPT + row] = s;
}

// ---------------- double-GELU(BN) ----------------------------------------------------------------
__global__ __launch_bounds__(256) void k_u(
    const float* __restrict__ in, const float* __restrict__ sc,
    const float* __restrict__ sh, float* __restrict__ out)
{
    const int c = blockIdx.y, b = blockIdx.z;
    const int n = (blockIdx.x * 256 + threadIdx.x) * 4;
    size_t i = ((size_t)b * CH + c) * NPT + n;
    float4 v = *reinterpret_cast<const float4*>(in + i);
    float s = sc[c], t = sh[c];
    float4 o;
    o.x = gelu_exact(gelu_exact(fmaf(v.x, s, t)));
    o.y = gelu_exact(gelu_exact(fmaf(v.y, s, t)));
    o.z = gelu_exact(gelu_exact(fmaf(v.z, s, t)));
    o.w = gelu_exact(gelu_exact(fmaf(v.w, s, t)));
    *reinterpret_cast<float4*>(out + i) = o;
}

// ---------------- MFMA kNN prefilter v6 -----------------------------------------------------------
// grid (NPT/32 * 2, BSZ): 128 q-tiles (32 q) x 2 m-halves. 4 waves/block:
// wave w: q-sub w>>1 (16 q), m-quarter w&1 (1024 m in 16-m tiles, 64 iters).
// __launch_bounds__(256,4): VGPR cap 128 (grid supplies exactly 4 waves/SIMD; don't starve regs).
// bq pinned per-iteration (blocks rematerialization). Insert = med3 pair-chain:
//   insert k into sorted (a,b): a'=min(a,k), b'=med3(a,b,k), carry=max(b,k)  -- 3 ops / 2 slots,
//   carry chain 8 deep (vs 16). Dual lists Q,R give 2 independent chains.
// key = sortable-u32(distance) top 20 bits | index (12 bits). NOTE: do NOT replace the sign-flip
// with a +C offset: at |d|~C the 12-bit key truncation granularity grows to 2^12*ulp(C) and
// destroys rank fidelity. Sign-flip keeps granularity ~0.125 at d~2^8.
__global__ __launch_bounds__(256, 4) void k_knn_mfma(
    const unsigned short* __restrict__ featbf, const float* __restrict__ sqv,
    int* __restrict__ idxh)
{
    __shared__ unsigned int mlist[4][16][17];
    const int tid  = threadIdx.x;
    const int wv   = tid >> 6;
    const int lane = tid & 63;
    const int r = lane & 15, g = lane >> 4;
    const int b    = blockIdx.y;
    const int qt   = blockIdx.x >> 1;
    const int half = blockIdx.x & 1;
    const int q0   = qt * 32 + (wv >> 1) * 16;
    const int mbase = half * 2048 + (wv & 1) * 1024;
    const unsigned short* fb = featbf + (size_t)b * NPT * CH;

    short8 bq0, bq1, bq2, bq3, bq4, bq5;
    {
        const unsigned short* qp = fb + (size_t)(q0 + r) * CH + g * 8;
        bq0 = *reinterpret_cast<const short8*>(qp);
        bq1 = *reinterpret_cast<const short8*>(qp + 32);
        bq2 = *reinterpret_cast<const short8*>(qp + 64);
        bq3 = *reinterpret_cast<const short8*>(qp + 96);
        bq4 = *reinterpret_cast<const short8*>(qp + 128);
        bq5 = *reinterpret_cast<const short8*>(qp + 160);
    }

    unsigned int Q[16], R[16];
    #pragma unroll
    for (int e = 0; e < 16; ++e){ Q[e] = 0xFFFFFFFFu; R[e] = 0xFFFFFFFFu; }

    const float* sq = sqv + b * NPT;
    const unsigned short* pa = fb + (size_t)(mbase + r) * CH + g * 8;

    for (int it = 0; it < 64; ++it){
        // pin the query fragments in VGPRs (defeat rematerialization/reload)
        asm volatile("" : "+v"(bq0), "+v"(bq1), "+v"(bq2), "+v"(bq3), "+v"(bq4), "+v"(bq5));

        const unsigned short* p = pa + (size_t)it * (16 * CH);
        short8 a0 = *reinterpret_cast<const short8*>(p);
        short8 a1 = *reinterpret_cast<const short8*>(p + 32);
        short8 a2 = *reinterpret_cast<const short8*>(p + 64);
        short8 a3 = *reinterpret_cast<const short8*>(p + 96);
        short8 a4 = *reinterpret_cast<const short8*>(p + 128);
        short8 a5 = *reinterpret_cast<const short8*>(p + 160);
        float4 s4 = *reinterpret_cast<const float4*>(sq + mbase + it * 16 + 4 * g);

        // two independent 3-deep MFMA chains (halve accumulator dependency)
        f32x4 accA = {0.f, 0.f, 0.f, 0.f};
        f32x4 accB = {0.f, 0.f, 0.f, 0.f};
        accA = __builtin_amdgcn_mfma_f32_16x16x32_bf16(a0, bq0, accA, 0, 0, 0);
        accB = __builtin_amdgcn_mfma_f32_16x16x32_bf16(a1, bq1, accB, 0, 0, 0);
        accA = __builtin_amdgcn_mfma_f32_16x16x32_bf16(a2, bq2, accA, 0, 0, 0);
        accB = __builtin_amdgcn_mfma_f32_16x16x32_bf16(a3, bq3, accB, 0, 0, 0);
        accA = __builtin_amdgcn_mfma_f32_16x16x32_bf16(a4, bq4, accA, 0, 0, 0);
        accB = __builtin_amdgcn_mfma_f32_16x16x32_bf16(a5, bq5, accB, 0, 0, 0);

        const int m0 = mbase + it * 16 + 4 * g;
        float sa[4] = {s4.x, s4.y, s4.z, s4.w};
        #pragma unroll
        for (int u = 0; u < 4; ++u){
            float d = fmaf(-2.0f, accA[u], fmaf(-2.0f, accB[u], sa[u]));
            int bb = __builtin_bit_cast(int, d);
            unsigned int uu = (unsigned int)(bb ^ ((bb >> 31) | 0x80000000));
            unsigned int k  = (uu & 0xFFFFF000u) | (unsigned int)(m0 + u);
            if (u & 1){
                #pragma unroll
                for (int pz = 0; pz < 8; ++pz){
                    unsigned int a = R[2 * pz], bv = R[2 * pz + 1];
                    R[2 * pz]     = umin_(a, k);
                    R[2 * pz + 1] = umed3_(a, bv, k);
                    k             = umax_(bv, k);
                }
            } else {
                #pragma unroll
                for (int pz = 0; pz < 8; ++pz){
                    unsigned int a = Q[2 * pz], bv = Q[2 * pz + 1];
                    Q[2 * pz]     = umin_(a, k);
                    Q[2 * pz + 1] = umed3_(a, bv, k);
                    k             = umax_(bv, k);
                }
            }
        }
    }

    // per-wave extraction: top-16 of Q ∪ R across the 4 g-lanes per query
    #pragma unroll 1
    for (int rd = 0; rd < 16; ++rd){
        unsigned int lq = Q[0], lr = R[0];
        unsigned int v = umin_(lq, lr);
        v = umin_(v, (unsigned int)__shfl_xor((int)v, 16));
        v = umin_(v, (unsigned int)__shfl_xor((int)v, 32));
        bool winq = (lq == v);
        bool winr = (lr == v) && !winq;
        if (winq){
            #pragma unroll
            for (int e = 0; e < 15; ++e) Q[e] = Q[e + 1];
            Q[15] = 0xFFFFFFFFu;
        } else if (winr){
            #pragma unroll
            for (int e = 0; e < 15; ++e) R[e] = R[e + 1];
            R[15] = 0xFFFFFFFFu;
        }
        if (g == 0) mlist[wv][r][rd] = v;
    }
    if (g == 0) mlist[wv][r][16] = 0xFFFFFFFFu;   // sentinel
    __syncthreads();

    // merge the 2 m-quarter lists per query -> top-20 for this half (keys unique)
    if (tid < 32){
        const int qq = tid;            // query within block (0..31)
        const int qs = qq >> 4, rr = qq & 15;
        int i0 = 0, i1 = 0;
        int* op = idxh + ((size_t)(b * NPT + qt * 32 + qq) * 2 + half) * KPH;
        for (int rd = 0; rd < KPH; ++rd){
            unsigned int k0 = mlist[qs * 2][rr][i0];
            unsigned int k1 = mlist[qs * 2 + 1][rr][i1];
            unsigned int mm = umin_(k0, k1);
            op[rd] = (int)(mm & 0xFFFu);
            i0 += (k0 == mm); i1 += (k1 == mm);
        }
    }
}

// ---------------- f64 re-rank of 40 candidates -> exact top-16 ----------------------------------
__global__ __launch_bounds__(64) void k_refine(
    const double* __restrict__ featT, const int* __restrict__ idxh, int* __restrict__ idxf)
{
    const int q = blockIdx.x, b = blockIdx.y, lane = threadIdx.x;
    const double* qv = featT + ((size_t)b * NPT + q) * CH;
    double q0 = qv[lane], q1 = qv[lane + 64], q2 = qv[lane + 128];
    double myd = INFINITY; int mym = 0x7fffffff;
    const int* cl = idxh + ((size_t)b * NPT + q) * KCAND;
    for (int t = 0; t < KCAND; ++t){
        int m = cl[t];
        const double* cv = featT + ((size_t)b * NPT + m) * CH;
        double d0 = cv[lane] - q0, d1 = cv[lane + 64] - q1, d2 = cv[lane + 128] - q2;
        double d = d0 * d0 + d1 * d1 + d2 * d2;
        #pragma unroll
        for (int off = 32; off; off >>= 1) d += __shfl_xor(d, off);
        if (lane == t){ myd = d; mym = m; }
    }
    for (int r = 0; r < KNB; ++r){
        double bv = myd; int bi = mym;
        #pragma unroll
        for (int off = 32; off; off >>= 1){
            double ov = __shfl_xor(bv, off);
            int    oi = __shfl_xor(bi, off);
            if (ov < bv || (ov == bv && oi < bi)){ bv = ov; bi = oi; }
        }
        if (lane == 0) idxf[((size_t)b * NPT + q) * KNB + r] = bi;
        if (mym == bi){ myd = INFINITY; mym = 0x7fffffff; }
    }
}

// ---------------- gather + BN0-apply + max-relative aggregate + channel interleave --------------
__global__ __launch_bounds__(256) void k_gather(
    const float* __restrict__ t1, const float* __restrict__ sc,
    const float* __restrict__ sh, const int* __restrict__ idx, float* __restrict__ hcat)
{
    __shared__ int il[KNB * 256];
    const int tid = threadIdx.x;
    const int n0  = blockIdx.x * 256;
    const int cg  = blockIdx.y;
    const int b   = blockIdx.z;
    for (int lin = tid; lin < 256 * KNB; lin += 256){
        int nl = lin >> 4, k = lin & 15;
        il[k * 256 + nl] = idx[((size_t)b * NPT + n0) * KNB + lin];
    }
    __syncthreads();
    const float* base = t1 + (size_t)b * CH * NPT;
    const int n = n0 + tid;
    for (int c = cg * 48; c < cg * 48 + 48; ++c){
        const float* row = base + (size_t)c * NPT;
        float s = sc[c], t = sh[c];
        float fi = fmaf(row[n], s, t);
        float mx = -INFINITY;
        #pragma unroll
        for (int k = 0; k < KNB; ++k){
            float v = fmaf(row[il[k * 256 + tid]], s, t);
            mx = fmaxf(mx, v - fi);
        }
        size_t o = ((size_t)b * 2 * CH + 2 * c) * NPT + n;
        hcat[o]       = fi;
        hcat[o + NPT] = mx;
    }
}

extern "C" void kernel_launch(void* const* d_in, const int* in_sizes, int n_in,
                              void* d_out, int out_size, void* d_ws, size_t ws_size,
                              hipStream_t stream)
{
    const float* x    = (const float*)d_in[0];
    const float* w1   = (const float*)d_in[1];
    const float* w2   = (const float*)d_in[2];
    const float* wmr  = (const float*)d_in[3];
    const float* bmr  = (const float*)d_in[4];
    const float* g0   = (const float*)d_in[5];
    const float* b0   = (const float*)d_in[6];
    const float* gm   = (const float*)d_in[7];
    const float* bm   = (const float*)d_in[8];
    const float* g1   = (const float*)d_in[9];
    const float* b1   = (const float*)d_in[10];
    float* outp = (float*)d_out;

    const size_t BCN = (size_t)BSZ * CH * NPT;
    float*  A     = (float*)d_ws;                       // BCN floats
    float*  Bb    = A + BCN;                            // BCN floats
    float*  Cc    = Bb + BCN;                           // 2*BCN floats
    double* t1d   = (double*)Cc;                        // BCN doubles (dead after k_tr64)
    unsigned short* featbf = (unsigned short*)Cc;       // BCN bf16 (alias; live knn only)
    double* featT = (double*)(Cc + 2 * BCN);            // BCN doubles
    float*  sqv   = (float*)(featT + BCN);              // B*N
    int*    idxh  = (int*)(sqv + (size_t)BSZ * NPT);    // B*N*40
    int*    idxf  = idxh + (size_t)BSZ * NPT * KCAND;   // B*N*16
    double* scd   = (double*)(idxf + (size_t)BSZ * NPT * KNB);
    float*  scb   = (float*)(scd + CH);
    float *sc0 = scb,          *sh0 = scb + CH;
    float *sc1 = scb + 2 * CH, *sh1 = scb + 3 * CH;
    float *sc2 = scb + 4 * CH, *sh2 = scb + 5 * CH;

    dim3 gg(NPT / 1024, CH / 8, BSZ);
    dim3 ge(NPT / 1024, CH, BSZ);

    // fc1 (f64 accumulate, dual fp32/f64 write)
    k_fc1_f64<<<gg, 256, 0, stream>>>(x, w1, A, t1d);
    // BN0 stats in f64
    k_stats_f64<<<CH, 256, 0, stream>>>(t1d, g0, b0, sc0, sh0, scd);
    // f64 scaled (shift-free) transposed features
    k_tr64<<<dim3(NPT / 32, CH / 32, BSZ), dim3(32, 8), 0, stream>>>(t1d, scd, featT);
    // bf16 features + fp32 sq norms (t1d dead; featbf overwrites it)
    k_bf_sq<<<dim3(NPT / 4, BSZ), 256, 0, stream>>>(featT, featbf, sqv);
    // kNN: MFMA bf16 prefilter (q-tile 32, 2 halves x top-20) -> f64 exact top-16
    k_knn_mfma<<<dim3(2 * NPT / 32, BSZ), 256, 0, stream>>>(featbf, sqv, idxh);
    k_refine<<<dim3(NPT, BSZ), 64, 0, stream>>>(featT, idxh, idxf);
    // gather with BN0 folded in (reads pre-BN t1) + aggregate + interleave
    k_gather<<<dim3(NPT / 256, 4, BSZ), 256, 0, stream>>>(A, sc0, sh0, idxf, Cc);
    // mr conv (K=384) + bias
    k_gemm<2 * CH, true, false, false><<<gg, 256, 0, stream>>>(Cc, wmr, bmr, nullptr, nullptr, nullptr, A);
    // BN1 stats, u = gelu(gelu(BN1(t2)))
    k_stats<<<CH, 256, 0, stream>>>(A, gm, bm, sc1, sh1);
    k_u<<<ge, 256, 0, stream>>>(A, sc1, sh1, Bb);
    // BN2 stats, fc2 with BN folded into input + residual
    k_stats<<<CH, 256, 0, stream>>>(Bb, g1, b1, sc2, sh2);
    k_gemm<CH, false, true, true><<<gg, 256, 0, stream>>>(Bb, w2, nullptr, sc2, sh2, x, outp);
}

// Round 9
// 578.999 us; speedup vs baseline: 1.1057x; 1.0813x over previous
//
#include <hip/hip_runtime.h>
#include <hip/hip_bf16.h>
#include <math.h>

#define BSZ 4
#define CH  192
#define NPT 4096
#define KNB 16
#define KPH 20              // kept per half
#define KCAND (2 * KPH)     // refine candidates

typedef short short8 __attribute__((ext_vector_type(8)));
typedef float f32x4  __attribute__((ext_vector_type(4)));

__device__ __forceinline__ float gelu_exact(float x){
    return 0.5f * x * (1.0f + erff(x * 0.70710678118654752440f));
}
__device__ __forceinline__ unsigned int umin_(unsigned int a, unsigned int b){ return a < b ? a : b; }
__device__ __forceinline__ unsigned int umax_(unsigned int a, unsigned int b){ return a < b ? b : a; }
__device__ __forceinline__ unsigned int umed3_(unsigned int a, unsigned int b, unsigned int c){
    unsigned int r;
    asm("v_med3_u32 %0, %1, %2, %3" : "=v"(r) : "v"(a), "v"(b), "v"(c));
    return r;
}

// ---------------- fp32 GEMM: out[b,o,n] = sum_c W[o,c] * in[b,c,n] (+bias)(+BN-fold)(+resid) ----
template<int KDIM, bool BIASED, bool SCALED, bool RESID>
__global__ __launch_bounds__(256) void k_gemm(
    const float* __restrict__ in, const float* __restrict__ W,
    const float* __restrict__ bias, const float* __restrict__ sc,
    const float* __restrict__ sh, const float* __restrict__ resid,
    float* __restrict__ out)
{
    constexpr int OT = 8, NT = 4;
    __shared__ float wtT[KDIM][OT];
    __shared__ float scl[SCALED ? KDIM : 1];
    __shared__ float shl[SCALED ? KDIM : 1];
    const int tid = threadIdx.x;
    const int o0  = blockIdx.y * OT;
    const int b   = blockIdx.z;
    const int n   = blockIdx.x * (256 * NT) + tid * NT;

    for (int lin = tid; lin < KDIM * OT; lin += 256){
        int c = lin >> 3, o = lin & 7;
        wtT[c][o] = W[(size_t)(o0 + o) * KDIM + c];
    }
    if (SCALED){
        for (int c = tid; c < KDIM; c += 256){ scl[c] = sc[c]; shl[c] = sh[c]; }
    }
    __syncthreads();

    float acc[OT][NT] = {};
    const float* ip = in + (size_t)b * KDIM * NPT + n;
    #pragma unroll 2
    for (int c = 0; c < KDIM; ++c){
        float4 x4 = *reinterpret_cast<const float4*>(ip + (size_t)c * NPT);
        float xv[NT] = {x4.x, x4.y, x4.z, x4.w};
        if (SCALED){
            #pragma unroll
            for (int j = 0; j < NT; ++j) xv[j] = fmaf(xv[j], scl[c], shl[c]);
        }
        float4 w0 = *reinterpret_cast<const float4*>(&wtT[c][0]);
        float4 w1 = *reinterpret_cast<const float4*>(&wtT[c][4]);
        float wv[OT] = {w0.x, w0.y, w0.z, w0.w, w1.x, w1.y, w1.z, w1.w};
        #pragma unroll
        for (int oo = 0; oo < OT; ++oo)
            #pragma unroll
            for (int j = 0; j < NT; ++j)
                acc[oo][j] = fmaf(wv[oo], xv[j], acc[oo][j]);
    }

    #pragma unroll
    for (int oo = 0; oo < OT; ++oo){
        size_t off = ((size_t)b * CH + o0 + oo) * NPT + n;
        float add = BIASED ? bias[o0 + oo] : 0.0f;
        float vals[4];
        #pragma unroll
        for (int j = 0; j < 4; ++j) vals[j] = acc[oo][j] + add;
        if (RESID){
            float4 r4 = *reinterpret_cast<const float4*>(resid + off);
            vals[0] += r4.x; vals[1] += r4.y; vals[2] += r4.z; vals[3] += r4.w;
        }
        float4 o4; o4.x = vals[0]; o4.y = vals[1]; o4.z = vals[2]; o4.w = vals[3];
        *reinterpret_cast<float4*>(out + off) = o4;
    }
}

// ---------------- fc1 with f64 accumulation -> f64 t1 only --------------------------------------
__global__ __launch_bounds__(256) void k_fc1_f64(
    const float* __restrict__ in, const float* __restrict__ W, double* __restrict__ outd)
{
    constexpr int OT = 8, NT = 4;
    __shared__ float wtT[CH][OT];
    const int tid = threadIdx.x;
    const int o0  = blockIdx.y * OT;
    const int b   = blockIdx.z;
    const int n   = blockIdx.x * (256 * NT) + tid * NT;

    for (int lin = tid; lin < CH * OT; lin += 256){
        int c = lin >> 3, o = lin & 7;
        wtT[c][o] = W[(size_t)(o0 + o) * CH + c];
    }
    __syncthreads();

    double acc[OT][NT] = {};
    const float* ip = in + (size_t)b * CH * NPT + n;
    for (int c = 0; c < CH; ++c){
        float4 x4 = *reinterpret_cast<const float4*>(ip + (size_t)c * NPT);
        double xv[NT] = {x4.x, x4.y, x4.z, x4.w};
        float4 w0 = *reinterpret_cast<const float4*>(&wtT[c][0]);
        float4 w1 = *reinterpret_cast<const float4*>(&wtT[c][4]);
        double wv[OT] = {w0.x, w0.y, w0.z, w0.w, w1.x, w1.y, w1.z, w1.w};
        #pragma unroll
        for (int oo = 0; oo < OT; ++oo)
            #pragma unroll
            for (int j = 0; j < NT; ++j)
                acc[oo][j] = fma(wv[oo], xv[j], acc[oo][j]);
    }

    #pragma unroll
    for (int oo = 0; oo < OT; ++oo){
        size_t off = ((size_t)b * CH + o0 + oo) * NPT + n;
        #pragma unroll
        for (int j = 0; j < 4; ++j) outd[off + j] = acc[oo][j];
    }
}

// ---------------- f64 BN0 stats: fp32 scale/shift + f64 scale for kNN ---------------------------
__global__ __launch_bounds__(256) void k_stats_f64(
    const double* __restrict__ t, const float* __restrict__ gamma,
    const float* __restrict__ beta, float* __restrict__ scale,
    float* __restrict__ shift, double* __restrict__ scd)
{
    const int c = blockIdx.x, tid = threadIdx.x;
    double s = 0., s2 = 0.;
    for (int b = 0; b < BSZ; ++b){
        const double* p = t + ((size_t)b * CH + c) * NPT;
        for (int n = tid; n < NPT; n += 256){ double v = p[n]; s += v; s2 += v * v; }
    }
    __shared__ double rs[256], rs2[256];
    rs[tid] = s; rs2[tid] = s2; __syncthreads();
    for (int off = 128; off; off >>= 1){
        if (tid < off){ rs[tid] += rs[tid + off]; rs2[tid] += rs2[tid + off]; }
        __syncthreads();
    }
    if (tid == 0){
        const double invn = 1.0 / (BSZ * NPT);
        double mean = rs[0] * invn;
        double var  = rs2[0] * invn - mean * mean;
        double rstd = 1.0 / sqrt(var + 1e-5);
        double s_   = rstd * (double)gamma[c];
        scale[c] = (float)s_;
        shift[c] = (float)((double)beta[c] - mean * s_);
        scd[c]   = s_;
    }
}

// ---------------- fp32 per-channel batch stats -> scale/shift -----------------------------------
__global__ __launch_bounds__(256) void k_stats(
    const float* __restrict__ t, const float* __restrict__ gamma,
    const float* __restrict__ beta, float* __restrict__ scale, float* __restrict__ shift)
{
    const int c = blockIdx.x, tid = threadIdx.x;
    float s = 0.f, s2 = 0.f;
    for (int b = 0; b < BSZ; ++b){
        const float* p = t + ((size_t)b * CH + c) * NPT;
        for (int n = tid; n < NPT; n += 256){ float v = p[n]; s += v; s2 += v * v; }
    }
    __shared__ float rs[256], rs2[256];
    rs[tid] = s; rs2[tid] = s2; __syncthreads();
    for (int off = 128; off; off >>= 1){
        if (tid < off){ rs[tid] += rs[tid + off]; rs2[tid] += rs2[tid + off]; }
        __syncthreads();
    }
    if (tid == 0){
        const float invn = 1.0f / (BSZ * NPT);
        float mean = rs[0] * invn;
        float var  = rs2[0] * invn - mean * mean;
        float rstd = rsqrtf(var + 1e-5f);
        float s_   = rstd * gamma[c];
        scale[c] = s_;
        shift[c] = beta[c] - mean * s_;
    }
}

// ---------------- transpose + per-channel f64 scale: featT[b][n][c] -----------------------------
__global__ void k_tr64(const double* __restrict__ t1d, const double* __restrict__ scd,
                       double* __restrict__ featT)
{
    __shared__ double tile[32][33];
    const int n0 = blockIdx.x * 32, c0 = blockIdx.y * 32, b = blockIdx.z;
    #pragma unroll
    for (int r = 0; r < 32; r += 8){
        int c = c0 + threadIdx.y + r, n = n0 + threadIdx.x;
        tile[threadIdx.y + r][threadIdx.x] = t1d[((size_t)b * CH + c) * NPT + n] * scd[c];
    }
    __syncthreads();
    #pragma unroll
    for (int r = 0; r < 32; r += 8){
        int n = n0 + threadIdx.y + r, c = c0 + threadIdx.x;
        featT[((size_t)b * NPT + n) * CH + c] = tile[threadIdx.x][threadIdx.y + r];
    }
}

// ---------------- featT (f64, shift-free) -> fp32 copy + bf16 features + fp32 sq norms ----------
__global__ __launch_bounds__(256) void k_bf_sq(
    const double* __restrict__ featT, unsigned short* __restrict__ featbf,
    float* __restrict__ feat32, float* __restrict__ sqv)
{
    const int wid  = threadIdx.x >> 6;
    const int lane = threadIdx.x & 63;
    const int row  = blockIdx.x * 4 + wid;
    const int b    = blockIdx.y;
    const double* p = featT + ((size_t)b * NPT + row) * CH;
    unsigned short* o = featbf + ((size_t)b * NPT + row) * CH;
    float* f32o = feat32 + ((size_t)b * NPT + row) * CH;
    float s = 0.f;
    #pragma unroll
    for (int j = 0; j < 3; ++j){
        float v = (float)p[lane + 64 * j];
        s = fmaf(v, v, s);
        f32o[lane + 64 * j] = v;
        unsigned int bits = __builtin_bit_cast(unsigned int, v);
        o[lane + 64 * j] = (unsigned short)((bits + 0x7fff + ((bits >> 16) & 1)) >> 16);
    }
    #pragma unroll
    for (int off = 32; off; off >>= 1) s += __shfl_xor(s, off);
    if (lane == 0) sqv[b * NPT + row] = s;
}

// ---------------- double-GELU(BN) ----------------------------------------------------------------
__global__ __launch_bounds__(256) void k_u(
    const float* __restrict__ in, const float* __restrict__ sc,
    const float* __restrict__ sh, float* __restrict__ out)
{
    const int c = blockIdx.y, b = blockIdx.z;
    const int n = (blockIdx.x * 256 + threadIdx.x) * 4;
    size_t i = ((size_t)b * CH + c) * NPT + n;
    float4 v = *reinterpret_cast<const float4*>(in + i);
    float s = sc[c], t = sh[c];
    float4 o;
    o.x = gelu_exact(gelu_exact(fmaf(v.x, s, t)));
    o.y = gelu_exact(gelu_exact(fmaf(v.y, s, t)));
    o.z = gelu_exact(gelu_exact(fmaf(v.z, s, t)));
    o.w = gelu_exact(gelu_exact(fmaf(v.w, s, t)));
    *reinterpret_cast<float4*>(out + i) = o;
}

// ---------------- MFMA kNN prefilter (unchanged from R8) ----------------------------------------
__global__ __launch_bounds__(256, 4) void k_knn_mfma(
    const unsigned short* __restrict__ featbf, const float* __restrict__ sqv,
    int* __restrict__ idxh)
{
    __shared__ unsigned int mlist[4][16][17];
    const int tid  = threadIdx.x;
    const int wv   = tid >> 6;
    const int lane = tid & 63;
    const int r = lane & 15, g = lane >> 4;
    const int b    = blockIdx.y;
    const int qt   = blockIdx.x >> 1;
    const int half = blockIdx.x & 1;
    const int q0   = qt * 32 + (wv >> 1) * 16;
    const int mbase = half * 2048 + (wv & 1) * 1024;
    const unsigned short* fb = featbf + (size_t)b * NPT * CH;

    short8 bq0, bq1, bq2, bq3, bq4, bq5;
    {
        const unsigned short* qp = fb + (size_t)(q0 + r) * CH + g * 8;
        bq0 = *reinterpret_cast<const short8*>(qp);
        bq1 = *reinterpret_cast<const short8*>(qp + 32);
        bq2 = *reinterpret_cast<const short8*>(qp + 64);
        bq3 = *reinterpret_cast<const short8*>(qp + 96);
        bq4 = *reinterpret_cast<const short8*>(qp + 128);
        bq5 = *reinterpret_cast<const short8*>(qp + 160);
    }

    unsigned int Q[16], R[16];
    #pragma unroll
    for (int e = 0; e < 16; ++e){ Q[e] = 0xFFFFFFFFu; R[e] = 0xFFFFFFFFu; }

    const float* sq = sqv + b * NPT;
    const unsigned short* pa = fb + (size_t)(mbase + r) * CH + g * 8;

    for (int it = 0; it < 64; ++it){
        asm volatile("" : "+v"(bq0), "+v"(bq1), "+v"(bq2), "+v"(bq3), "+v"(bq4), "+v"(bq5));

        const unsigned short* p = pa + (size_t)it * (16 * CH);
        short8 a0 = *reinterpret_cast<const short8*>(p);
        short8 a1 = *reinterpret_cast<const short8*>(p + 32);
        short8 a2 = *reinterpret_cast<const short8*>(p + 64);
        short8 a3 = *reinterpret_cast<const short8*>(p + 96);
        short8 a4 = *reinterpret_cast<const short8*>(p + 128);
        short8 a5 = *reinterpret_cast<const short8*>(p + 160);
        float4 s4 = *reinterpret_cast<const float4*>(sq + mbase + it * 16 + 4 * g);

        f32x4 accA = {0.f, 0.f, 0.f, 0.f};
        f32x4 accB = {0.f, 0.f, 0.f, 0.f};
        accA = __builtin_amdgcn_mfma_f32_16x16x32_bf16(a0, bq0, accA, 0, 0, 0);
        accB = __builtin_amdgcn_mfma_f32_16x16x32_bf16(a1, bq1, accB, 0, 0, 0);
        accA = __builtin_amdgcn_mfma_f32_16x16x32_bf16(a2, bq2, accA, 0, 0, 0);
        accB = __builtin_amdgcn_mfma_f32_16x16x32_bf16(a3, bq3, accB, 0, 0, 0);
        accA = __builtin_amdgcn_mfma_f32_16x16x32_bf16(a4, bq4, accA, 0, 0, 0);
        accB = __builtin_amdgcn_mfma_f32_16x16x32_bf16(a5, bq5, accB, 0, 0, 0);

        const int m0 = mbase + it * 16 + 4 * g;
        float sa[4] = {s4.x, s4.y, s4.z, s4.w};
        #pragma unroll
        for (int u = 0; u < 4; ++u){
            float d = fmaf(-2.0f, accA[u], fmaf(-2.0f, accB[u], sa[u]));
            int bb = __builtin_bit_cast(int, d);
            unsigned int uu = (unsigned int)(bb ^ ((bb >> 31) | 0x80000000));
            unsigned int k  = (uu & 0xFFFFF000u) | (unsigned int)(m0 + u);
            if (u & 1){
                #pragma unroll
                for (int pz = 0; pz < 8; ++pz){
                    unsigned int a = R[2 * pz], bv = R[2 * pz + 1];
                    R[2 * pz]     = umin_(a, k);
                    R[2 * pz + 1] = umed3_(a, bv, k);
                    k             = umax_(bv, k);
                }
            } else {
                #pragma unroll
                for (int pz = 0; pz < 8; ++pz){
                    unsigned int a = Q[2 * pz], bv = Q[2 * pz + 1];
                    Q[2 * pz]     = umin_(a, k);
                    Q[2 * pz + 1] = umed3_(a, bv, k);
                    k             = umax_(bv, k);
                }
            }
        }
    }

    #pragma unroll 1
    for (int rd = 0; rd < 16; ++rd){
        unsigned int lq = Q[0], lr = R[0];
        unsigned int v = umin_(lq, lr);
        v = umin_(v, (unsigned int)__shfl_xor((int)v, 16));
        v = umin_(v, (unsigned int)__shfl_xor((int)v, 32));
        bool winq = (lq == v);
        bool winr = (lr == v) && !winq;
        if (winq){
            #pragma unroll
            for (int e = 0; e < 15; ++e) Q[e] = Q[e + 1];
            Q[15] = 0xFFFFFFFFu;
        } else if (winr){
            #pragma unroll
            for (int e = 0; e < 15; ++e) R[e] = R[e + 1];
            R[15] = 0xFFFFFFFFu;
        }
        if (g == 0) mlist[wv][r][rd] = v;
    }
    if (g == 0) mlist[wv][r][16] = 0xFFFFFFFFu;
    __syncthreads();

    if (tid < 32){
        const int qq = tid;
        const int qs = qq >> 4, rr = qq & 15;
        int i0 = 0, i1 = 0;
        int* op = idxh + ((size_t)(b * NPT + qt * 32 + qq) * 2 + half) * KPH;
        for (int rd = 0; rd < KPH; ++rd){
            unsigned int k0 = mlist[qs * 2][rr][i0];
            unsigned int k1 = mlist[qs * 2 + 1][rr][i1];
            unsigned int mm = umin_(k0, k1);
            op[rd] = (int)(mm & 0xFFFu);
            i0 += (k0 == mm); i1 += (k1 == mm);
        }
    }
}

// ---------------- fp32 refine of 40 candidates -> top-16 + borderline flag ----------------------
__global__ __launch_bounds__(64) void k_refine32(
    const float* __restrict__ feat32, const int* __restrict__ idxh,
    int* __restrict__ idxf, int* __restrict__ flags)
{
    const int q = blockIdx.x, b = blockIdx.y, lane = threadIdx.x;
    const float* qv = feat32 + ((size_t)b * NPT + q) * CH;
    float q0 = qv[lane], q1 = qv[lane + 64], q2 = qv[lane + 128];
    float myd = INFINITY; int mym = 0x7fffffff;
    const int* cl = idxh + ((size_t)b * NPT + q) * KCAND;
    for (int t = 0; t < KCAND; ++t){
        int m = cl[t];
        const float* cv = feat32 + ((size_t)b * NPT + m) * CH;
        float d0 = cv[lane] - q0, d1 = cv[lane + 64] - q1, d2 = cv[lane + 128] - q2;
        float d = fmaf(d0, d0, fmaf(d1, d1, d2 * d2));
        #pragma unroll
        for (int off = 32; off; off >>= 1) d += __shfl_xor(d, off);
        if (lane == t){ myd = d; mym = m; }
    }
    float d16 = 0.f;
    for (int r = 0; r < KNB; ++r){
        float bv = myd; int bi = mym;
        #pragma unroll
        for (int off = 32; off; off >>= 1){
            float ov = __shfl_xor(bv, off);
            int   oi = __shfl_xor(bi, off);
            if (ov < bv || (ov == bv && oi < bi)){ bv = ov; bi = oi; }
        }
        if (lane == 0) idxf[((size_t)b * NPT + q) * KNB + r] = bi;
        if (mym == bi){ myd = INFINITY; mym = 0x7fffffff; }
        d16 = bv;
    }
    // 17th-smallest remaining
    float bv = myd;
    #pragma unroll
    for (int off = 32; off; off >>= 1){
        float ov = __shfl_xor(bv, off);
        bv = fminf(bv, ov);
    }
    if (lane == 0){
        float eps = 1e-3f + 2e-4f * d16;
        flags[(size_t)b * NPT + q] = (bv - d16 < eps) ? 1 : 0;
    }
}

// ---------------- f64 exact refine for flagged (borderline) queries only ------------------------
__global__ __launch_bounds__(64) void k_refine64(
    const double* __restrict__ featT, const int* __restrict__ idxh,
    int* __restrict__ idxf, const int* __restrict__ flags)
{
    const int q = blockIdx.x, b = blockIdx.y, lane = threadIdx.x;
    if (flags[(size_t)b * NPT + q] == 0) return;
    const double* qv = featT + ((size_t)b * NPT + q) * CH;
    double q0 = qv[lane], q1 = qv[lane + 64], q2 = qv[lane + 128];
    double myd = INFINITY; int mym = 0x7fffffff;
    const int* cl = idxh + ((size_t)b * NPT + q) * KCAND;
    for (int t = 0; t < KCAND; ++t){
        int m = cl[t];
        const double* cv = featT + ((size_t)b * NPT + m) * CH;
        double d0 = cv[lane] - q0, d1 = cv[lane + 64] - q1, d2 = cv[lane + 128] - q2;
        double d = d0 * d0 + d1 * d1 + d2 * d2;
        #pragma unroll
        for (int off = 32; off; off >>= 1) d += __shfl_xor(d, off);
        if (lane == t){ myd = d; mym = m; }
    }
    for (int r = 0; r < KNB; ++r){
        double bv = myd; int bi = mym;
        #pragma unroll
        for (int off = 32; off; off >>= 1){
            double ov = __shfl_xor(bv, off);
            int    oi = __shfl_xor(bi, off);
            if (ov < bv || (ov == bv && oi < bi)){ bv = ov; bi = oi; }
        }
        if (lane == 0) idxf[((size_t)b * NPT + q) * KNB + r] = bi;
        if (mym == bi){ myd = INFINITY; mym = 0x7fffffff; }
    }
}

// ---------------- gather v2: coalesced rows from feat32 + LDS-transposed hcat write -------------
// grid (NPT/32, 2 c-chunks of 96, BSZ), 128 threads. thread = (nl = tid>>2, sub = tid&3).
// fi = feat32[n][c] + sh[c]; mx = max_k(feat32[idx_k][c] - feat32[n][c])  (BN shift cancels).
__global__ __launch_bounds__(128) void k_gather2(
    const float* __restrict__ feat32, const float* __restrict__ sh0,
    const int* __restrict__ idx, float* __restrict__ hcat)
{
    __shared__ float lt[192 * 33];
    __shared__ int il[32 * KNB];
    const int tid = threadIdx.x;
    const int n0  = blockIdx.x * 32;
    const int cg  = blockIdx.y;
    const int b   = blockIdx.z;

    for (int i = tid; i < 32 * KNB; i += 128)
        il[i] = idx[((size_t)b * NPT + n0) * KNB + i];
    __syncthreads();

    const int nl = tid >> 2, sub = tid & 3;
    const int n  = n0 + nl;
    const float* fbase = feat32 + (size_t)b * NPT * CH;
    const float* qr = fbase + (size_t)n * CH + cg * 96;

    float4 qv[6], mx[6];
    #pragma unroll
    for (int j = 0; j < 6; ++j){
        qv[j] = *reinterpret_cast<const float4*>(qr + (sub + 4 * j) * 4);
        mx[j] = make_float4(-INFINITY, -INFINITY, -INFINITY, -INFINITY);
    }

    #pragma unroll 4
    for (int k = 0; k < KNB; ++k){
        const float* cr = fbase + (size_t)il[nl * KNB + k] * CH + cg * 96;
        #pragma unroll
        for (int j = 0; j < 6; ++j){
            float4 v = *reinterpret_cast<const float4*>(cr + (sub + 4 * j) * 4);
            mx[j].x = fmaxf(mx[j].x, v.x - qv[j].x);
            mx[j].y = fmaxf(mx[j].y, v.y - qv[j].y);
            mx[j].z = fmaxf(mx[j].z, v.z - qv[j].z);
            mx[j].w = fmaxf(mx[j].w, v.w - qv[j].w);
        }
    }

    #pragma unroll
    for (int j = 0; j < 6; ++j){
        const int cb = (sub + 4 * j) * 4;               // local c base (0..95)
        float4 s4 = *reinterpret_cast<const float4*>(sh0 + cg * 96 + cb);
        float fi[4] = {qv[j].x + s4.x, qv[j].y + s4.y, qv[j].z + s4.z, qv[j].w + s4.w};
        float mm[4] = {mx[j].x, mx[j].y, mx[j].z, mx[j].w};
        #pragma unroll
        for (int e = 0; e < 4; ++e){
            int cl = cb + e;
            lt[(2 * cl) * 33 + nl]     = fi[e];
            lt[(2 * cl + 1) * 33 + nl] = mm[e];
        }
    }
    __syncthreads();

    // write out 192 channel-rows x 32 n, coalesced
    const int rsub = tid >> 5;       // 0..3
    const int ni   = tid & 31;
    for (int r0 = 0; r0 < 192; r0 += 4){
        int row = r0 + rsub;
        int ch  = cg * 192 + row;
        hcat[((size_t)b * 2 * CH + ch) * NPT + n0 + ni] = lt[row * 33 + ni];
    }
}

extern "C" void kernel_launch(void* const* d_in, const int* in_sizes, int n_in,
                              void* d_out, int out_size, void* d_ws, size_t ws_size,
                              hipStream_t stream)
{
    const float* x    = (const float*)d_in[0];
    const float* w1   = (const float*)d_in[1];
    const float* w2   = (const float*)d_in[2];
    const float* wmr  = (const float*)d_in[3];
    const float* bmr  = (const float*)d_in[4];
    const float* g0   = (const float*)d_in[5];
    const float* b0   = (const float*)d_in[6];
    const float* gm   = (const float*)d_in[7];
    const float* bm   = (const float*)d_in[8];
    const float* g1   = (const float*)d_in[9];
    const float* b1   = (const float*)d_in[10];
    float* outp = (float*)d_out;

    const size_t BCN = (size_t)BSZ * CH * NPT;
    float*  A      = (float*)d_ws;                       // BCN f32: t2
    float*  Bb     = A + BCN;                            // BCN f32: u
    float*  Cc     = Bb + BCN;                           // 2*BCN f32: hcat; aliases t1d / featbf
    double* t1d    = (double*)Cc;                        // BCN f64 (dead after k_tr64)
    unsigned short* featbf = (unsigned short*)Cc;        // BCN bf16 (live during knn only)
    double* featT  = (double*)(Cc + 2 * BCN);            // BCN f64
    float*  feat32 = (float*)(featT + BCN);              // BCN f32
    float*  sqv    = feat32 + BCN;                       // B*N
    int*    idxh   = (int*)(sqv + (size_t)BSZ * NPT);    // B*N*40
    int*    idxf   = idxh + (size_t)BSZ * NPT * KCAND;   // B*N*16
    int*    flags  = idxf + (size_t)BSZ * NPT * KNB;     // B*N
    double* scd    = (double*)(flags + (size_t)BSZ * NPT);
    float*  scb    = (float*)(scd + CH);
    float *sc0 = scb,          *sh0 = scb + CH;
    float *sc1 = scb + 2 * CH, *sh1 = scb + 3 * CH;
    float *sc2 = scb + 4 * CH, *sh2 = scb + 5 * CH;

    dim3 gg(NPT / 1024, CH / 8, BSZ);
    dim3 ge(NPT / 1024, CH, BSZ);

    // fc1 (f64 accumulate)
    k_fc1_f64<<<gg, 256, 0, stream>>>(x, w1, t1d);
    // BN0 stats in f64
    k_stats_f64<<<CH, 256, 0, stream>>>(t1d, g0, b0, sc0, sh0, scd);
    // f64 scaled (shift-free) transposed features
    k_tr64<<<dim3(NPT / 32, CH / 32, BSZ), dim3(32, 8), 0, stream>>>(t1d, scd, featT);
    // fp32 copy + bf16 features + fp32 sq norms (t1d dead; featbf overwrites it)
    k_bf_sq<<<dim3(NPT / 4, BSZ), 256, 0, stream>>>(featT, featbf, feat32, sqv);
    // kNN: MFMA bf16 prefilter (2 halves x top-20)
    k_knn_mfma<<<dim3(2 * NPT / 32, BSZ), 256, 0, stream>>>(featbf, sqv, idxh);
    // fp32 refine (+ borderline flag) then exact f64 refine on flagged only
    k_refine32<<<dim3(NPT, BSZ), 64, 0, stream>>>(feat32, idxh, idxf, flags);
    k_refine64<<<dim3(NPT, BSZ), 64, 0, stream>>>(featT, idxh, idxf, flags);
    // gather v2 (coalesced; overwrites featbf region -> hcat)
    k_gather2<<<dim3(NPT / 32, 2, BSZ), 128, 0, stream>>>(feat32, sh0, idxf, Cc);
    // mr conv (K=384) + bias
    k_gemm<2 * CH, true, false, false><<<gg, 256, 0, stream>>>(Cc, wmr, bmr, nullptr, nullptr, nullptr, A);
    // BN1 stats, u = gelu(gelu(BN1(t2)))
    k_stats<<<CH, 256, 0, stream>>>(A, gm, bm, sc1, sh1);
    k_u<<<ge, 256, 0, stream>>>(A, sc1, sh1, Bb);
    // BN2 stats, fc2 with BN folded into input + residual
    k_stats<<<CH, 256, 0, stream>>>(Bb, g1, b1, sc2, sh2);
    k_gemm<CH, false, true, true><<<gg, 256, 0, stream>>>(Bb, w2, nullptr, sc2, sh2, x, outp);
}

// Round 10
// 544.210 us; speedup vs baseline: 1.1764x; 1.0639x over previous
//
#include <hip/hip_runtime.h>
#include <hip/hip_bf16.h>
#include <math.h>

#define BSZ 4
#define CH  192
#define NPT 4096
#define KNB 16
#define KPH 20              // kept per half
#define KCAND (2 * KPH)     // refine candidates
#define NTOT ((float)(BSZ * NPT))

typedef short short8 __attribute__((ext_vector_type(8)));
typedef float f32x4  __attribute__((ext_vector_type(4)));

__device__ __forceinline__ float gelu_exact(float x){
    return 0.5f * x * (1.0f + erff(x * 0.70710678118654752440f));
}
__device__ __forceinline__ unsigned int umin_(unsigned int a, unsigned int b){ return a < b ? a : b; }
__device__ __forceinline__ unsigned int umax_(unsigned int a, unsigned int b){ return a < b ? b : a; }
__device__ __forceinline__ unsigned int umed3_(unsigned int a, unsigned int b, unsigned int c){
    unsigned int r;
    asm("v_med3_u32 %0, %1, %2, %3" : "=v"(r) : "v"(a), "v"(b), "v"(c));
    return r;
}
__device__ __forceinline__ unsigned short bf16rnd(float v){
    unsigned int bits = __builtin_bit_cast(unsigned int, v);
    return (unsigned short)((bits + 0x7fff + ((bits >> 16) & 1)) >> 16);
}

// ---------------- fc1 with f64 accumulation -> f64 t1 -------------------------------------------
__global__ __launch_bounds__(256) void k_fc1_f64(
    const float* __restrict__ in, const float* __restrict__ W, double* __restrict__ outd)
{
    constexpr int OT = 8, NT = 4;
    __shared__ float wtT[CH][OT];
    const int tid = threadIdx.x;
    const int o0  = blockIdx.y * OT;
    const int b   = blockIdx.z;
    const int n   = blockIdx.x * (256 * NT) + tid * NT;

    for (int lin = tid; lin < CH * OT; lin += 256){
        int c = lin >> 3, o = lin & 7;
        wtT[c][o] = W[(size_t)(o0 + o) * CH + c];
    }
    __syncthreads();

    double acc[OT][NT] = {};
    const float* ip = in + (size_t)b * CH * NPT + n;
    for (int c = 0; c < CH; ++c){
        float4 x4 = *reinterpret_cast<const float4*>(ip + (size_t)c * NPT);
        double xv[NT] = {x4.x, x4.y, x4.z, x4.w};
        float4 w0 = *reinterpret_cast<const float4*>(&wtT[c][0]);
        float4 w1 = *reinterpret_cast<const float4*>(&wtT[c][4]);
        double wv[OT] = {w0.x, w0.y, w0.z, w0.w, w1.x, w1.y, w1.z, w1.w};
        #pragma unroll
        for (int oo = 0; oo < OT; ++oo)
            #pragma unroll
            for (int j = 0; j < NT; ++j)
                acc[oo][j] = fma(wv[oo], xv[j], acc[oo][j]);
    }

    #pragma unroll
    for (int oo = 0; oo < OT; ++oo){
        size_t off = ((size_t)b * CH + o0 + oo) * NPT + n;
        #pragma unroll
        for (int j = 0; j < 4; ++j) outd[off + j] = acc[oo][j];
    }
}

// ---------------- f64 BN0 stats: fp32 scale/shift + f64 scale -----------------------------------
__global__ __launch_bounds__(256) void k_stats_f64(
    const double* __restrict__ t, const float* __restrict__ gamma,
    const float* __restrict__ beta, float* __restrict__ scale,
    float* __restrict__ shift, double* __restrict__ scd)
{
    const int c = blockIdx.x, tid = threadIdx.x;
    double s = 0., s2 = 0.;
    for (int b = 0; b < BSZ; ++b){
        const double* p = t + ((size_t)b * CH + c) * NPT;
        for (int n = tid; n < NPT; n += 256){ double v = p[n]; s += v; s2 += v * v; }
    }
    __shared__ double rs[256], rs2[256];
    rs[tid] = s; rs2[tid] = s2; __syncthreads();
    for (int off = 128; off; off >>= 1){
        if (tid < off){ rs[tid] += rs[tid + off]; rs2[tid] += rs2[tid + off]; }
        __syncthreads();
    }
    if (tid == 0){
        const double invn = 1.0 / (BSZ * NPT);
        double mean = rs[0] * invn;
        double var  = rs2[0] * invn - mean * mean;
        double rstd = 1.0 / sqrt(var + 1e-5);
        double s_   = rstd * (double)gamma[c];
        scale[c] = (float)s_;
        shift[c] = (float)((double)beta[c] - mean * s_);
        scd[c]   = s_;
    }
}

// ---------------- fused: transpose+scale -> featT(f64), feat32, featbf(bf16), sqv ---------------
// grid (NPT/32, BSZ), block (32,8)
__global__ void k_feat(
    const double* __restrict__ t1d, const double* __restrict__ scd,
    double* __restrict__ featT, float* __restrict__ feat32,
    unsigned short* __restrict__ featbf, float* __restrict__ sqv)
{
    __shared__ double tile[32][33];
    __shared__ float sqp[32][33];
    const int n0 = blockIdx.x * 32, b = blockIdx.y;
    const int tx = threadIdx.x, ty = threadIdx.y;
    float part[4] = {0.f, 0.f, 0.f, 0.f};

    for (int cc = 0; cc < CH / 32; ++cc){
        const int cbase = cc * 32;
        #pragma unroll
        for (int r = 0; r < 32; r += 8){
            int c = cbase + ty + r;
            tile[ty + r][tx] = t1d[((size_t)b * CH + c) * NPT + n0 + tx] * scd[c];
        }
        __syncthreads();
        #pragma unroll
        for (int r = 0; r < 32; r += 8){
            int n = n0 + ty + r;
            int c = cbase + tx;
            double v = tile[tx][ty + r];
            size_t o = ((size_t)b * NPT + n) * CH + c;
            featT[o] = v;
            float f = (float)v;
            feat32[o] = f;
            featbf[o] = bf16rnd(f);
            part[r >> 3] = fmaf(f, f, part[r >> 3]);
        }
        __syncthreads();
    }
    #pragma unroll
    for (int j = 0; j < 4; ++j) sqp[ty + 8 * j][tx] = part[j];
    __syncthreads();
    if (ty == 0){
        float s = 0.f;
        #pragma unroll 8
        for (int k = 0; k < 32; ++k) s += sqp[tx][k];
        sqv[b * NPT + n0 + tx] = s;
    }
}

// ---------------- MFMA kNN prefilter v7: q-tile 64, 8 waves -------------------------------------
// grid (2*NPT/64, BSZ), 512 threads. wave w: q-sub (w>>1) of 16 q, m-quarter (w&1) of 1024 m.
// All 4 q-sub waves of a quarter read the same m rows -> L1 sharing; block L2 traffic 4x lower.
__global__ __launch_bounds__(512, 4) void k_knn_mfma(
    const unsigned short* __restrict__ featbf, const float* __restrict__ sqv,
    int* __restrict__ idxh)
{
    __shared__ unsigned int mlist[8][16][17];
    const int tid  = threadIdx.x;
    const int wv   = tid >> 6;
    const int lane = tid & 63;
    const int r = lane & 15, g = lane >> 4;
    const int b    = blockIdx.y;
    const int qt   = blockIdx.x >> 1;
    const int half = blockIdx.x & 1;
    const int q0   = qt * 64 + (wv >> 1) * 16;
    const int mbase = half * 2048 + (wv & 1) * 1024;
    const unsigned short* fb = featbf + (size_t)b * NPT * CH;

    short8 bq0, bq1, bq2, bq3, bq4, bq5;
    {
        const unsigned short* qp = fb + (size_t)(q0 + r) * CH + g * 8;
        bq0 = *reinterpret_cast<const short8*>(qp);
        bq1 = *reinterpret_cast<const short8*>(qp + 32);
        bq2 = *reinterpret_cast<const short8*>(qp + 64);
        bq3 = *reinterpret_cast<const short8*>(qp + 96);
        bq4 = *reinterpret_cast<const short8*>(qp + 128);
        bq5 = *reinterpret_cast<const short8*>(qp + 160);
    }

    unsigned int Q[16], R[16];
    #pragma unroll
    for (int e = 0; e < 16; ++e){ Q[e] = 0xFFFFFFFFu; R[e] = 0xFFFFFFFFu; }

    const float* sq = sqv + b * NPT;
    const unsigned short* pa = fb + (size_t)(mbase + r) * CH + g * 8;

    for (int it = 0; it < 64; ++it){
        asm volatile("" : "+v"(bq0), "+v"(bq1), "+v"(bq2), "+v"(bq3), "+v"(bq4), "+v"(bq5));

        const unsigned short* p = pa + (size_t)it * (16 * CH);
        short8 a0 = *reinterpret_cast<const short8*>(p);
        short8 a1 = *reinterpret_cast<const short8*>(p + 32);
        short8 a2 = *reinterpret_cast<const short8*>(p + 64);
        short8 a3 = *reinterpret_cast<const short8*>(p + 96);
        short8 a4 = *reinterpret_cast<const short8*>(p + 128);
        short8 a5 = *reinterpret_cast<const short8*>(p + 160);
        float4 s4 = *reinterpret_cast<const float4*>(sq + mbase + it * 16 + 4 * g);

        f32x4 accA = {0.f, 0.f, 0.f, 0.f};
        f32x4 accB = {0.f, 0.f, 0.f, 0.f};
        accA = __builtin_amdgcn_mfma_f32_16x16x32_bf16(a0, bq0, accA, 0, 0, 0);
        accB = __builtin_amdgcn_mfma_f32_16x16x32_bf16(a1, bq1, accB, 0, 0, 0);
        accA = __builtin_amdgcn_mfma_f32_16x16x32_bf16(a2, bq2, accA, 0, 0, 0);
        accB = __builtin_amdgcn_mfma_f32_16x16x32_bf16(a3, bq3, accB, 0, 0, 0);
        accA = __builtin_amdgcn_mfma_f32_16x16x32_bf16(a4, bq4, accA, 0, 0, 0);
        accB = __builtin_amdgcn_mfma_f32_16x16x32_bf16(a5, bq5, accB, 0, 0, 0);

        const int m0 = mbase + it * 16 + 4 * g;
        float sa[4] = {s4.x, s4.y, s4.z, s4.w};
        #pragma unroll
        for (int u = 0; u < 4; ++u){
            float d = fmaf(-2.0f, accA[u], fmaf(-2.0f, accB[u], sa[u]));
            int bb = __builtin_bit_cast(int, d);
            unsigned int uu = (unsigned int)(bb ^ ((bb >> 31) | 0x80000000));
            unsigned int k  = (uu & 0xFFFFF000u) | (unsigned int)(m0 + u);
            if (u & 1){
                #pragma unroll
                for (int pz = 0; pz < 8; ++pz){
                    unsigned int a = R[2 * pz], bv = R[2 * pz + 1];
                    R[2 * pz]     = umin_(a, k);
                    R[2 * pz + 1] = umed3_(a, bv, k);
                    k             = umax_(bv, k);
                }
            } else {
                #pragma unroll
                for (int pz = 0; pz < 8; ++pz){
                    unsigned int a = Q[2 * pz], bv = Q[2 * pz + 1];
                    Q[2 * pz]     = umin_(a, k);
                    Q[2 * pz + 1] = umed3_(a, bv, k);
                    k             = umax_(bv, k);
                }
            }
        }
    }

    // per-wave extraction: top-16 of Q ∪ R across the 4 g-lanes per query
    #pragma unroll 1
    for (int rd = 0; rd < 16; ++rd){
        unsigned int lq = Q[0], lr = R[0];
        unsigned int v = umin_(lq, lr);
        v = umin_(v, (unsigned int)__shfl_xor((int)v, 16));
        v = umin_(v, (unsigned int)__shfl_xor((int)v, 32));
        bool winq = (lq == v);
        bool winr = (lr == v) && !winq;
        if (winq){
            #pragma unroll
            for (int e = 0; e < 15; ++e) Q[e] = Q[e + 1];
            Q[15] = 0xFFFFFFFFu;
        } else if (winr){
            #pragma unroll
            for (int e = 0; e < 15; ++e) R[e] = R[e + 1];
            R[15] = 0xFFFFFFFFu;
        }
        if (g == 0) mlist[wv][r][rd] = v;
    }
    if (g == 0) mlist[wv][r][16] = 0xFFFFFFFFu;   // sentinel
    __syncthreads();

    // merge the 2 m-quarter lists per query -> top-20 for this half (keys unique)
    if (tid < 64){
        const int qs = tid >> 4, rr = tid & 15;
        int i0 = 0, i1 = 0;
        int* op = idxh + ((size_t)(b * NPT + qt * 64 + tid) * 2 + half) * KPH;
        for (int rd = 0; rd < KPH; ++rd){
            unsigned int k0 = mlist[qs * 2][rr][i0];
            unsigned int k1 = mlist[qs * 2 + 1][rr][i1];
            unsigned int mm = umin_(k0, k1);
            op[rd] = (int)(mm & 0xFFFu);
            i0 += (k0 == mm); i1 += (k1 == mm);
        }
    }
}

// ---------------- fused refine: fp32 top-16 + certified f64 fallback ----------------------------
__global__ __launch_bounds__(64) void k_refine(
    const float* __restrict__ feat32, const double* __restrict__ featT,
    const int* __restrict__ idxh, int* __restrict__ idxf)
{
    const int q = blockIdx.x, b = blockIdx.y, lane = threadIdx.x;
    const int* cl = idxh + ((size_t)b * NPT + q) * KCAND;
    const float* qv = feat32 + ((size_t)b * NPT + q) * CH;
    float q0 = qv[lane], q1 = qv[lane + 64], q2 = qv[lane + 128];
    float myd = INFINITY; int mym = 0x7fffffff;
    for (int t = 0; t < KCAND; ++t){
        int m = cl[t];
        const float* cv = feat32 + ((size_t)b * NPT + m) * CH;
        float d0 = cv[lane] - q0, d1 = cv[lane + 64] - q1, d2 = cv[lane + 128] - q2;
        float d = fmaf(d0, d0, fmaf(d1, d1, d2 * d2));
        #pragma unroll
        for (int off = 32; off; off >>= 1) d += __shfl_xor(d, off);
        if (lane == t){ myd = d; mym = m; }
    }
    float d16 = 0.f;
    for (int r = 0; r < KNB; ++r){
        float bv = myd; int bi = mym;
        #pragma unroll
        for (int off = 32; off; off >>= 1){
            float ov = __shfl_xor(bv, off);
            int   oi = __shfl_xor(bi, off);
            if (ov < bv || (ov == bv && oi < bi)){ bv = ov; bi = oi; }
        }
        if (lane == 0) idxf[((size_t)b * NPT + q) * KNB + r] = bi;
        if (mym == bi){ myd = INFINITY; mym = 0x7fffffff; }
        d16 = bv;
    }
    float b17 = myd;
    #pragma unroll
    for (int off = 32; off; off >>= 1) b17 = fminf(b17, __shfl_xor(b17, off));
    int flag = (b17 - d16 < 1e-3f + 2e-4f * d16) ? 1 : 0;
    flag = __shfl(flag, 0);
    if (!flag) return;

    // exact f64 re-rank (rare, whole block)
    const double* qvd = featT + ((size_t)b * NPT + q) * CH;
    double Q0 = qvd[lane], Q1 = qvd[lane + 64], Q2 = qvd[lane + 128];
    double mydd = INFINITY; int mymd = 0x7fffffff;
    for (int t = 0; t < KCAND; ++t){
        int m = cl[t];
        const double* cv = featT + ((size_t)b * NPT + m) * CH;
        double d0 = cv[lane] - Q0, d1 = cv[lane + 64] - Q1, d2 = cv[lane + 128] - Q2;
        double d = d0 * d0 + d1 * d1 + d2 * d2;
        #pragma unroll
        for (int off = 32; off; off >>= 1) d += __shfl_xor(d, off);
        if (lane == t){ mydd = d; mymd = m; }
    }
    for (int r = 0; r < KNB; ++r){
        double bv = mydd; int bi = mymd;
        #pragma unroll
        for (int off = 32; off; off >>= 1){
            double ov = __shfl_xor(bv, off);
            int    oi = __shfl_xor(bi, off);
            if (ov < bv || (ov == bv && oi < bi)){ bv = ov; bi = oi; }
        }
        if (lane == 0) idxf[((size_t)b * NPT + q) * KNB + r] = bi;
        if (mymd == bi){ mydd = INFINITY; mymd = 0x7fffffff; }
    }
}

// ---------------- gather v2 (unchanged): coalesced rows + LDS-transposed hcat write -------------
__global__ __launch_bounds__(128) void k_gather2(
    const float* __restrict__ feat32, const float* __restrict__ sh0,
    const int* __restrict__ idx, float* __restrict__ hcat)
{
    __shared__ float lt[192 * 33];
    __shared__ int il[32 * KNB];
    const int tid = threadIdx.x;
    const int n0  = blockIdx.x * 32;
    const int cg  = blockIdx.y;
    const int b   = blockIdx.z;

    for (int i = tid; i < 32 * KNB; i += 128)
        il[i] = idx[((size_t)b * NPT + n0) * KNB + i];
    __syncthreads();

    const int nl = tid >> 2, sub = tid & 3;
    const int n  = n0 + nl;
    const float* fbase = feat32 + (size_t)b * NPT * CH;
    const float* qr = fbase + (size_t)n * CH + cg * 96;

    float4 qv[6], mx[6];
    #pragma unroll
    for (int j = 0; j < 6; ++j){
        qv[j] = *reinterpret_cast<const float4*>(qr + (sub + 4 * j) * 4);
        mx[j] = make_float4(-INFINITY, -INFINITY, -INFINITY, -INFINITY);
    }

    #pragma unroll 4
    for (int k = 0; k < KNB; ++k){
        const float* cr = fbase + (size_t)il[nl * KNB + k] * CH + cg * 96;
        #pragma unroll
        for (int j = 0; j < 6; ++j){
            float4 v = *reinterpret_cast<const float4*>(cr + (sub + 4 * j) * 4);
            mx[j].x = fmaxf(mx[j].x, v.x - qv[j].x);
            mx[j].y = fmaxf(mx[j].y, v.y - qv[j].y);
            mx[j].z = fmaxf(mx[j].z, v.z - qv[j].z);
            mx[j].w = fmaxf(mx[j].w, v.w - qv[j].w);
        }
    }

    #pragma unroll
    for (int j = 0; j < 6; ++j){
        const int cb = (sub + 4 * j) * 4;
        float4 s4 = *reinterpret_cast<const float4*>(sh0 + cg * 96 + cb);
        float fi[4] = {qv[j].x + s4.x, qv[j].y + s4.y, qv[j].z + s4.z, qv[j].w + s4.w};
        float mm[4] = {mx[j].x, mx[j].y, mx[j].z, mx[j].w};
        #pragma unroll
        for (int e = 0; e < 4; ++e){
            int cl = cb + e;
            lt[(2 * cl) * 33 + nl]     = fi[e];
            lt[(2 * cl + 1) * 33 + nl] = mm[e];
        }
    }
    __syncthreads();

    const int rsub = tid >> 5;
    const int ni   = tid & 31;
    for (int r0 = 0; r0 < 192; r0 += 4){
        int row = r0 + rsub;
        int ch  = cg * 192 + row;
        hcat[((size_t)b * 2 * CH + ch) * NPT + n0 + ni] = lt[row * 33 + ni];
    }
}

// ---------------- mr-conv GEMM (K=384) + bias, with fused BN1-stat atomics ----------------------
__global__ __launch_bounds__(256) void k_gemm_mr(
    const float* __restrict__ in, const float* __restrict__ W, const float* __restrict__ bias,
    float* __restrict__ out, float* __restrict__ s1sum, float* __restrict__ s1sq)
{
    constexpr int KDIM = 2 * CH, OT = 8, NT = 4;
    __shared__ float wtT[KDIM][OT];
    __shared__ float redS[4][8], redQ[4][8];
    const int tid = threadIdx.x;
    const int o0  = blockIdx.y * OT;
    const int b   = blockIdx.z;
    const int n   = blockIdx.x * (256 * NT) + tid * NT;

    for (int lin = tid; lin < KDIM * OT; lin += 256){
        int c = lin >> 3, o = lin & 7;
        wtT[c][o] = W[(size_t)(o0 + o) * KDIM + c];
    }
    __syncthreads();

    float acc[OT][NT] = {};
    const float* ip = in + (size_t)b * KDIM * NPT + n;
    #pragma unroll 2
    for (int c = 0; c < KDIM; ++c){
        float4 x4 = *reinterpret_cast<const float4*>(ip + (size_t)c * NPT);
        float xv[NT] = {x4.x, x4.y, x4.z, x4.w};
        float4 w0 = *reinterpret_cast<const float4*>(&wtT[c][0]);
        float4 w1 = *reinterpret_cast<const float4*>(&wtT[c][4]);
        float wv[OT] = {w0.x, w0.y, w0.z, w0.w, w1.x, w1.y, w1.z, w1.w};
        #pragma unroll
        for (int oo = 0; oo < OT; ++oo)
            #pragma unroll
            for (int j = 0; j < NT; ++j)
                acc[oo][j] = fmaf(wv[oo], xv[j], acc[oo][j]);
    }

    float ps[OT], pq[OT];
    #pragma unroll
    for (int oo = 0; oo < OT; ++oo){
        size_t off = ((size_t)b * CH + o0 + oo) * NPT + n;
        float add = bias[o0 + oo];
        float vals[4];
        float s = 0.f, q = 0.f;
        #pragma unroll
        for (int j = 0; j < 4; ++j){
            vals[j] = acc[oo][j] + add;
            s += vals[j];
            q = fmaf(vals[j], vals[j], q);
        }
        ps[oo] = s; pq[oo] = q;
        float4 o4; o4.x = vals[0]; o4.y = vals[1]; o4.z = vals[2]; o4.w = vals[3];
        *reinterpret_cast<float4*>(out + off) = o4;
    }

    #pragma unroll
    for (int oo = 0; oo < OT; ++oo){
        #pragma unroll
        for (int off = 32; off; off >>= 1){
            ps[oo] += __shfl_xor(ps[oo], off);
            pq[oo] += __shfl_xor(pq[oo], off);
        }
    }
    const int wv = tid >> 6, lane = tid & 63;
    if (lane == 0){
        #pragma unroll
        for (int oo = 0; oo < OT; ++oo){ redS[wv][oo] = ps[oo]; redQ[wv][oo] = pq[oo]; }
    }
    __syncthreads();
    if (tid < 8){
        float s = redS[0][tid] + redS[1][tid] + redS[2][tid] + redS[3][tid];
        float q = redQ[0][tid] + redQ[1][tid] + redQ[2][tid] + redQ[3][tid];
        atomicAdd(&s1sum[o0 + tid], s);
        atomicAdd(&s1sq[o0 + tid], q);
    }
}

// ---------------- u = gelu(gelu(BN1(t2))), BN1 from sums; fused BN2-stat atomics ----------------
__global__ __launch_bounds__(256) void k_u(
    const float* __restrict__ in, const float* __restrict__ s1sum, const float* __restrict__ s1sq,
    const float* __restrict__ gm, const float* __restrict__ bm,
    float* __restrict__ out, float* __restrict__ s2sum, float* __restrict__ s2sq)
{
    __shared__ float redS[4], redQ[4];
    const int c = blockIdx.y, b = blockIdx.z;
    const int n = (blockIdx.x * 256 + threadIdx.x) * 4;
    const float invn = 1.0f / NTOT;
    float mean = s1sum[c] * invn;
    float var  = s1sq[c] * invn - mean * mean;
    float rstd = rsqrtf(var + 1e-5f);
    float s = rstd * gm[c], t = bm[c] - mean * s;

    size_t i = ((size_t)b * CH + c) * NPT + n;
    float4 v = *reinterpret_cast<const float4*>(in + i);
    float4 o;
    o.x = gelu_exact(gelu_exact(fmaf(v.x, s, t)));
    o.y = gelu_exact(gelu_exact(fmaf(v.y, s, t)));
    o.z = gelu_exact(gelu_exact(fmaf(v.z, s, t)));
    o.w = gelu_exact(gelu_exact(fmaf(v.w, s, t)));
    *reinterpret_cast<float4*>(out + i) = o;

    float ps = o.x + o.y + o.z + o.w;
    float pq = fmaf(o.x, o.x, fmaf(o.y, o.y, fmaf(o.z, o.z, o.w * o.w)));
    #pragma unroll
    for (int off = 32; off; off >>= 1){
        ps += __shfl_xor(ps, off);
        pq += __shfl_xor(pq, off);
    }
    const int wv = threadIdx.x >> 6, lane = threadIdx.x & 63;
    if (lane == 0){ redS[wv] = ps; redQ[wv] = pq; }
    __syncthreads();
    if (threadIdx.x == 0){
        atomicAdd(&s2sum[c], redS[0] + redS[1] + redS[2] + redS[3]);
        atomicAdd(&s2sq[c],  redQ[0] + redQ[1] + redQ[2] + redQ[3]);
    }
}

// ---------------- fc2 GEMM with BN2 (from sums) folded into input + residual --------------------
__global__ __launch_bounds__(256) void k_gemm_fc2(
    const float* __restrict__ in, const float* __restrict__ W,
    const float* __restrict__ s2sum, const float* __restrict__ s2sq,
    const float* __restrict__ g1, const float* __restrict__ b1,
    const float* __restrict__ resid, float* __restrict__ out)
{
    constexpr int KDIM = CH, OT = 8, NT = 4;
    __shared__ float wtT[KDIM][OT];
    __shared__ float scl[KDIM], shl[KDIM];
    const int tid = threadIdx.x;
    const int o0  = blockIdx.y * OT;
    const int b   = blockIdx.z;
    const int n   = blockIdx.x * (256 * NT) + tid * NT;

    for (int lin = tid; lin < KDIM * OT; lin += 256){
        int c = lin >> 3, o = lin & 7;
        wtT[c][o] = W[(size_t)(o0 + o) * KDIM + c];
    }
    const float invn = 1.0f / NTOT;
    for (int c = tid; c < KDIM; c += 256){
        float mean = s2sum[c] * invn;
        float var  = s2sq[c] * invn - mean * mean;
        float rstd = rsqrtf(var + 1e-5f);
        float s = rstd * g1[c];
        scl[c] = s;
        shl[c] = b1[c] - mean * s;
    }
    __syncthreads();

    float acc[OT][NT] = {};
    const float* ip = in + (size_t)b * KDIM * NPT + n;
    #pragma unroll 2
    for (int c = 0; c < KDIM; ++c){
        float4 x4 = *reinterpret_cast<const float4*>(ip + (size_t)c * NPT);
        float xv[NT];
        xv[0] = fmaf(x4.x, scl[c], shl[c]);
        xv[1] = fmaf(x4.y, scl[c], shl[c]);
        xv[2] = fmaf(x4.z, scl[c], shl[c]);
        xv[3] = fmaf(x4.w, scl[c], shl[c]);
        float4 w0 = *reinterpret_cast<const float4*>(&wtT[c][0]);
        float4 w1 = *reinterpret_cast<const float4*>(&wtT[c][4]);
        float wv[OT] = {w0.x, w0.y, w0.z, w0.w, w1.x, w1.y, w1.z, w1.w};
        #pragma unroll
        for (int oo = 0; oo < OT; ++oo)
            #pragma unroll
            for (int j = 0; j < NT; ++j)
                acc[oo][j] = fmaf(wv[oo], xv[j], acc[oo][j]);
    }

    #pragma unroll
    for (int oo = 0; oo < OT; ++oo){
        size_t off = ((size_t)b * CH + o0 + oo) * NPT + n;
        float4 r4 = *reinterpret_cast<const float4*>(resid + off);
        float4 o4;
        o4.x = acc[oo][0] + r4.x; o4.y = acc[oo][1] + r4.y;
        o4.z = acc[oo][2] + r4.z; o4.w = acc[oo][3] + r4.w;
        *reinterpret_cast<float4*>(out + off) = o4;
    }
}

extern "C" void kernel_launch(void* const* d_in, const int* in_sizes, int n_in,
                              void* d_out, int out_size, void* d_ws, size_t ws_size,
                              hipStream_t stream)
{
    const float* x    = (const float*)d_in[0];
    const float* w1   = (const float*)d_in[1];
    const float* w2   = (const float*)d_in[2];
    const float* wmr  = (const float*)d_in[3];
    const float* bmr  = (const float*)d_in[4];
    const float* g0   = (const float*)d_in[5];
    const float* b0   = (const float*)d_in[6];
    const float* gm   = (const float*)d_in[7];
    const float* bm   = (const float*)d_in[8];
    const float* g1   = (const float*)d_in[9];
    const float* b1   = (const float*)d_in[10];
    float* outp = (float*)d_out;

    const size_t BCN = (size_t)BSZ * CH * NPT;
    float*  A      = (float*)d_ws;                       // BCN f32: t2
    float*  Bb     = A + BCN;                            // BCN f32: featbf (bf16) -> u
    unsigned short* featbf = (unsigned short*)Bb;
    float*  Cc     = Bb + BCN;                           // 2*BCN f32: t1d (f64) -> hcat
    double* t1d    = (double*)Cc;
    double* featT  = (double*)(Cc + 2 * BCN);            // BCN f64
    float*  feat32 = (float*)(featT + BCN);              // BCN f32
    float*  sqv    = feat32 + BCN;                       // B*N
    int*    idxh   = (int*)(sqv + (size_t)BSZ * NPT);    // B*N*40
    int*    idxf   = idxh + (size_t)BSZ * NPT * KCAND;   // B*N*16
    float*  bnacc  = (float*)(idxf + (size_t)BSZ * NPT * KNB);  // 4*CH f32
    float *s1sum = bnacc, *s1sq = bnacc + CH, *s2sum = bnacc + 2 * CH, *s2sq = bnacc + 3 * CH;
    double* scd    = (double*)(bnacc + 4 * CH);
    float*  scb    = (float*)(scd + CH);
    float *sc0 = scb, *sh0 = scb + CH;

    dim3 gg(NPT / 1024, CH / 8, BSZ);
    dim3 ge(NPT / 1024, CH, BSZ);

    hipMemsetAsync(bnacc, 0, 4 * CH * sizeof(float), stream);
    // fc1 (f64 accumulate)
    k_fc1_f64<<<gg, 256, 0, stream>>>(x, w1, t1d);
    // BN0 stats in f64
    k_stats_f64<<<CH, 256, 0, stream>>>(t1d, g0, b0, sc0, sh0, scd);
    // fused transpose/scale -> featT + feat32 + featbf + sqv
    k_feat<<<dim3(NPT / 32, BSZ), dim3(32, 8), 0, stream>>>(t1d, scd, featT, feat32, featbf, sqv);
    // kNN prefilter (q-tile 64, 8 waves)
    k_knn_mfma<<<dim3(2 * NPT / 64, BSZ), 512, 0, stream>>>(featbf, sqv, idxh);
    // fused refine (fp32 + certified f64 fallback)
    k_refine<<<dim3(NPT, BSZ), 64, 0, stream>>>(feat32, featT, idxh, idxf);
    // gather (coalesced; writes hcat over dead t1d)
    k_gather2<<<dim3(NPT / 32, 2, BSZ), 128, 0, stream>>>(feat32, sh0, idxf, Cc);
    // mr conv + bias + BN1-stat atomics
    k_gemm_mr<<<gg, 256, 0, stream>>>(Cc, wmr, bmr, A, s1sum, s1sq);
    // u = gelu(gelu(BN1(t2))) + BN2-stat atomics
    k_u<<<ge, 256, 0, stream>>>(A, s1sum, s1sq, gm, bm, Bb, s2sum, s2sq);
    // fc2 with BN2 folded + residual
    k_gemm_fc2<<<gg, 256, 0, stream>>>(Bb, w2, s2sum, s2sq, g1, b1, x, outp);
}

// Round 11
// 542.769 us; speedup vs baseline: 1.1795x; 1.0027x over previous
//
#include <hip/hip_runtime.h>
#include <hip/hip_bf16.h>
#include <math.h>

#define BSZ 4
#define CH  192
#define NPT 4096
#define KNB 16
#define KPH 20              // kept per half
#define KCAND (2 * KPH)     // refine candidates
#define NTOT ((float)(BSZ * NPT))

typedef short short8 __attribute__((ext_vector_type(8)));
typedef float f32x4  __attribute__((ext_vector_type(4)));

__device__ __forceinline__ float gelu_exact(float x){
    return 0.5f * x * (1.0f + erff(x * 0.70710678118654752440f));
}
__device__ __forceinline__ unsigned int umin_(unsigned int a, unsigned int b){ return a < b ? a : b; }
__device__ __forceinline__ unsigned int umax_(unsigned int a, unsigned int b){ return a < b ? b : a; }
__device__ __forceinline__ unsigned short bf16rnd(float v){
    unsigned int bits = __builtin_bit_cast(unsigned int, v);
    return (unsigned short)((bits + 0x7fff + ((bits >> 16) & 1)) >> 16);
}

// ---------------- fc1 with f64 accumulation -> f64 t1 -------------------------------------------
__global__ __launch_bounds__(256) void k_fc1_f64(
    const float* __restrict__ in, const float* __restrict__ W, double* __restrict__ outd)
{
    constexpr int OT = 8, NT = 4;
    __shared__ float wtT[CH][OT];
    const int tid = threadIdx.x;
    const int o0  = blockIdx.y * OT;
    const int b   = blockIdx.z;
    const int n   = blockIdx.x * (256 * NT) + tid * NT;

    for (int lin = tid; lin < CH * OT; lin += 256){
        int c = lin >> 3, o = lin & 7;
        wtT[c][o] = W[(size_t)(o0 + o) * CH + c];
    }
    __syncthreads();

    double acc[OT][NT] = {};
    const float* ip = in + (size_t)b * CH * NPT + n;
    for (int c = 0; c < CH; ++c){
        float4 x4 = *reinterpret_cast<const float4*>(ip + (size_t)c * NPT);
        double xv[NT] = {x4.x, x4.y, x4.z, x4.w};
        float4 w0 = *reinterpret_cast<const float4*>(&wtT[c][0]);
        float4 w1 = *reinterpret_cast<const float4*>(&wtT[c][4]);
        double wv[OT] = {w0.x, w0.y, w0.z, w0.w, w1.x, w1.y, w1.z, w1.w};
        #pragma unroll
        for (int oo = 0; oo < OT; ++oo)
            #pragma unroll
            for (int j = 0; j < NT; ++j)
                acc[oo][j] = fma(wv[oo], xv[j], acc[oo][j]);
    }

    #pragma unroll
    for (int oo = 0; oo < OT; ++oo){
        size_t off = ((size_t)b * CH + o0 + oo) * NPT + n;
        #pragma unroll
        for (int j = 0; j < 4; ++j) outd[off + j] = acc[oo][j];
    }
}

// ---------------- f64 BN0 stats: fp32 scale/shift + f64 scale -----------------------------------
__global__ __launch_bounds__(256) void k_stats_f64(
    const double* __restrict__ t, const float* __restrict__ gamma,
    const float* __restrict__ beta, float* __restrict__ scale,
    float* __restrict__ shift, double* __restrict__ scd)
{
    const int c = blockIdx.x, tid = threadIdx.x;
    double s = 0., s2 = 0.;
    for (int b = 0; b < BSZ; ++b){
        const double* p = t + ((size_t)b * CH + c) * NPT;
        for (int n = tid; n < NPT; n += 256){ double v = p[n]; s += v; s2 += v * v; }
    }
    __shared__ double rs[256], rs2[256];
    rs[tid] = s; rs2[tid] = s2; __syncthreads();
    for (int off = 128; off; off >>= 1){
        if (tid < off){ rs[tid] += rs[tid + off]; rs2[tid] += rs2[tid + off]; }
        __syncthreads();
    }
    if (tid == 0){
        const double invn = 1.0 / (BSZ * NPT);
        double mean = rs[0] * invn;
        double var  = rs2[0] * invn - mean * mean;
        double rstd = 1.0 / sqrt(var + 1e-5);
        double s_   = rstd * (double)gamma[c];
        scale[c] = (float)s_;
        shift[c] = (float)((double)beta[c] - mean * s_);
        scd[c]   = s_;
    }
}

// ---------------- fused: transpose+scale -> featT(f64), feat32, featbf(bf16), sqv ---------------
__global__ void k_feat(
    const double* __restrict__ t1d, const double* __restrict__ scd,
    double* __restrict__ featT, float* __restrict__ feat32,
    unsigned short* __restrict__ featbf, float* __restrict__ sqv)
{
    __shared__ double tile[32][33];
    __shared__ float sqp[32][33];
    const int n0 = blockIdx.x * 32, b = blockIdx.y;
    const int tx = threadIdx.x, ty = threadIdx.y;
    float part[4] = {0.f, 0.f, 0.f, 0.f};

    for (int cc = 0; cc < CH / 32; ++cc){
        const int cbase = cc * 32;
        #pragma unroll
        for (int r = 0; r < 32; r += 8){
            int c = cbase + ty + r;
            tile[ty + r][tx] = t1d[((size_t)b * CH + c) * NPT + n0 + tx] * scd[c];
        }
        __syncthreads();
        #pragma unroll
        for (int r = 0; r < 32; r += 8){
            int n = n0 + ty + r;
            int c = cbase + tx;
            double v = tile[tx][ty + r];
            size_t o = ((size_t)b * NPT + n) * CH + c;
            featT[o] = v;
            float f = (float)v;
            feat32[o] = f;
            featbf[o] = bf16rnd(f);
            part[r >> 3] = fmaf(f, f, part[r >> 3]);
        }
        __syncthreads();
    }
    #pragma unroll
    for (int j = 0; j < 4; ++j) sqp[ty + 8 * j][tx] = part[j];
    __syncthreads();
    if (ty == 0){
        float s = 0.f;
        #pragma unroll 8
        for (int k = 0; k < 32; ++k) s += sqp[tx][k];
        sqv[b * NPT + n0 + tx] = s;
    }
}

// ---------------- MFMA kNN prefilter v8: minimal-register single-list ---------------------------
// grid (2*NPT/32, BSZ), 256 threads. wave w: q-sub (w>>1) of 16 q, m-quarter (w&1) of 1024 m.
// Single 16-deep sorted packed-key list per lane (depth-16 per lane stream provably contains
// every true top-16 member of the half). Plain min/max bubble, no inline asm, no pipelining —
// minimize register demand so Q + bq stay in VGPRs (target: VGPR_Count >= ~70, no scratch).
// key = sortable-u32(distance) top 20 bits | index (12 bits); globally unique.
__global__ __launch_bounds__(256, 4) void k_knn_mfma(
    const unsigned short* __restrict__ featbf, const float* __restrict__ sqv,
    int* __restrict__ idxh)
{
    __shared__ unsigned int mlist[4][16][17];
    const int tid  = threadIdx.x;
    const int wv   = tid >> 6;
    const int lane = tid & 63;
    const int r = lane & 15, g = lane >> 4;
    const int b    = blockIdx.y;
    const int qt   = blockIdx.x >> 1;
    const int half = blockIdx.x & 1;
    const int q0   = qt * 32 + (wv >> 1) * 16;
    const int mbase = half * 2048 + (wv & 1) * 1024;
    const unsigned short* fb = featbf + (size_t)b * NPT * CH;

    short8 bq0, bq1, bq2, bq3, bq4, bq5;
    {
        const unsigned short* qp = fb + (size_t)(q0 + r) * CH + g * 8;
        bq0 = *reinterpret_cast<const short8*>(qp);
        bq1 = *reinterpret_cast<const short8*>(qp + 32);
        bq2 = *reinterpret_cast<const short8*>(qp + 64);
        bq3 = *reinterpret_cast<const short8*>(qp + 96);
        bq4 = *reinterpret_cast<const short8*>(qp + 128);
        bq5 = *reinterpret_cast<const short8*>(qp + 160);
    }

    unsigned int Q[16];
    #pragma unroll
    for (int e = 0; e < 16; ++e) Q[e] = 0xFFFFFFFFu;

    const float* sq = sqv + b * NPT;
    const unsigned short* pa = fb + (size_t)(mbase + r) * CH + g * 8;

    for (int it = 0; it < 64; ++it){
        const unsigned short* p = pa + (size_t)it * (16 * CH);
        short8 a0 = *reinterpret_cast<const short8*>(p);
        short8 a1 = *reinterpret_cast<const short8*>(p + 32);
        short8 a2 = *reinterpret_cast<const short8*>(p + 64);
        short8 a3 = *reinterpret_cast<const short8*>(p + 96);
        short8 a4 = *reinterpret_cast<const short8*>(p + 128);
        short8 a5 = *reinterpret_cast<const short8*>(p + 160);
        float4 s4 = *reinterpret_cast<const float4*>(sq + mbase + it * 16 + 4 * g);

        f32x4 acc = {0.f, 0.f, 0.f, 0.f};
        acc = __builtin_amdgcn_mfma_f32_16x16x32_bf16(a0, bq0, acc, 0, 0, 0);
        acc = __builtin_amdgcn_mfma_f32_16x16x32_bf16(a1, bq1, acc, 0, 0, 0);
        acc = __builtin_amdgcn_mfma_f32_16x16x32_bf16(a2, bq2, acc, 0, 0, 0);
        acc = __builtin_amdgcn_mfma_f32_16x16x32_bf16(a3, bq3, acc, 0, 0, 0);
        acc = __builtin_amdgcn_mfma_f32_16x16x32_bf16(a4, bq4, acc, 0, 0, 0);
        acc = __builtin_amdgcn_mfma_f32_16x16x32_bf16(a5, bq5, acc, 0, 0, 0);

        const int m0 = mbase + it * 16 + 4 * g;
        float sa[4] = {s4.x, s4.y, s4.z, s4.w};
        #pragma unroll
        for (int u = 0; u < 4; ++u){
            float d = fmaf(-2.0f, acc[u], sa[u]);
            int bb = __builtin_bit_cast(int, d);
            unsigned int uu = (unsigned int)(bb ^ ((bb >> 31) | 0x80000000));
            unsigned int k  = (uu & 0xFFFFF000u) | (unsigned int)(m0 + u);
            #pragma unroll
            for (int e = 0; e < 16; ++e){
                unsigned int qe = Q[e];
                Q[e] = umin_(k, qe);
                k    = umax_(k, qe);
            }
        }
    }

    // per-wave extraction: top-16 across the 4 g-lanes per query (keys unique)
    #pragma unroll 1
    for (int rd = 0; rd < 16; ++rd){
        unsigned int v = Q[0];
        v = umin_(v, (unsigned int)__shfl_xor((int)v, 16));
        v = umin_(v, (unsigned int)__shfl_xor((int)v, 32));
        bool win = (Q[0] == v);
        if (win){
            #pragma unroll
            for (int e = 0; e < 15; ++e) Q[e] = Q[e + 1];
            Q[15] = 0xFFFFFFFFu;
        }
        if (g == 0) mlist[wv][r][rd] = v;
    }
    if (g == 0) mlist[wv][r][16] = 0xFFFFFFFFu;   // sentinel
    __syncthreads();

    // merge the 2 m-quarter lists per query -> top-20 for this half (keys unique)
    if (tid < 32){
        const int qq = tid;
        const int qs = qq >> 4, rr = qq & 15;
        int i0 = 0, i1 = 0;
        int* op = idxh + ((size_t)(b * NPT + qt * 32 + qq) * 2 + half) * KPH;
        for (int rd = 0; rd < KPH; ++rd){
            unsigned int k0 = mlist[qs * 2][rr][i0];
            unsigned int k1 = mlist[qs * 2 + 1][rr][i1];
            unsigned int mm = umin_(k0, k1);
            op[rd] = (int)(mm & 0xFFFu);
            i0 += (k0 == mm); i1 += (k1 == mm);
        }
    }
}

// ---------------- fused refine: fp32 top-16 + certified f64 fallback ----------------------------
__global__ __launch_bounds__(64) void k_refine(
    const float* __restrict__ feat32, const double* __restrict__ featT,
    const int* __restrict__ idxh, int* __restrict__ idxf)
{
    const int q = blockIdx.x, b = blockIdx.y, lane = threadIdx.x;
    const int* cl = idxh + ((size_t)b * NPT + q) * KCAND;
    const float* qv = feat32 + ((size_t)b * NPT + q) * CH;
    float q0 = qv[lane], q1 = qv[lane + 64], q2 = qv[lane + 128];
    float myd = INFINITY; int mym = 0x7fffffff;
    for (int t = 0; t < KCAND; ++t){
        int m = cl[t];
        const float* cv = feat32 + ((size_t)b * NPT + m) * CH;
        float d0 = cv[lane] - q0, d1 = cv[lane + 64] - q1, d2 = cv[lane + 128] - q2;
        float d = fmaf(d0, d0, fmaf(d1, d1, d2 * d2));
        #pragma unroll
        for (int off = 32; off; off >>= 1) d += __shfl_xor(d, off);
        if (lane == t){ myd = d; mym = m; }
    }
    float d16 = 0.f;
    for (int r = 0; r < KNB; ++r){
        float bv = myd; int bi = mym;
        #pragma unroll
        for (int off = 32; off; off >>= 1){
            float ov = __shfl_xor(bv, off);
            int   oi = __shfl_xor(bi, off);
            if (ov < bv || (ov == bv && oi < bi)){ bv = ov; bi = oi; }
        }
        if (lane == 0) idxf[((size_t)b * NPT + q) * KNB + r] = bi;
        if (mym == bi){ myd = INFINITY; mym = 0x7fffffff; }
        d16 = bv;
    }
    float b17 = myd;
    #pragma unroll
    for (int off = 32; off; off >>= 1) b17 = fminf(b17, __shfl_xor(b17, off));
    int flag = (b17 - d16 < 1e-3f + 2e-4f * d16) ? 1 : 0;
    flag = __shfl(flag, 0);
    if (!flag) return;

    // exact f64 re-rank (rare, whole block)
    const double* qvd = featT + ((size_t)b * NPT + q) * CH;
    double Q0 = qvd[lane], Q1 = qvd[lane + 64], Q2 = qvd[lane + 128];
    double mydd = INFINITY; int mymd = 0x7fffffff;
    for (int t = 0; t < KCAND; ++t){
        int m = cl[t];
        const double* cv = featT + ((size_t)b * NPT + m) * CH;
        double d0 = cv[lane] - Q0, d1 = cv[lane + 64] - Q1, d2 = cv[lane + 128] - Q2;
        double d = d0 * d0 + d1 * d1 + d2 * d2;
        #pragma unroll
        for (int off = 32; off; off >>= 1) d += __shfl_xor(d, off);
        if (lane == t){ mydd = d; mymd = m; }
    }
    for (int r = 0; r < KNB; ++r){
        double bv = mydd; int bi = mymd;
        #pragma unroll
        for (int off = 32; off; off >>= 1){
            double ov = __shfl_xor(bv, off);
            int    oi = __shfl_xor(bi, off);
            if (ov < bv || (ov == bv && oi < bi)){ bv = ov; bi = oi; }
        }
        if (lane == 0) idxf[((size_t)b * NPT + q) * KNB + r] = bi;
        if (mymd == bi){ mydd = INFINITY; mymd = 0x7fffffff; }
    }
}

// ---------------- gather v2: coalesced rows + LDS-transposed hcat write -------------------------
__global__ __launch_bounds__(128) void k_gather2(
    const float* __restrict__ feat32, const float* __restrict__ sh0,
    const int* __restrict__ idx, float* __restrict__ hcat)
{
    __shared__ float lt[192 * 33];
    __shared__ int il[32 * KNB];
    const int tid = threadIdx.x;
    const int n0  = blockIdx.x * 32;
    const int cg  = blockIdx.y;
    const int b   = blockIdx.z;

    for (int i = tid; i < 32 * KNB; i += 128)
        il[i] = idx[((size_t)b * NPT + n0) * KNB + i];
    __syncthreads();

    const int nl = tid >> 2, sub = tid & 3;
    const int n  = n0 + nl;
    const float* fbase = feat32 + (size_t)b * NPT * CH;
    const float* qr = fbase + (size_t)n * CH + cg * 96;

    float4 qv[6], mx[6];
    #pragma unroll
    for (int j = 0; j < 6; ++j){
        qv[j] = *reinterpret_cast<const float4*>(qr + (sub + 4 * j) * 4);
        mx[j] = make_float4(-INFINITY, -INFINITY, -INFINITY, -INFINITY);
    }

    #pragma unroll 4
    for (int k = 0; k < KNB; ++k){
        const float* cr = fbase + (size_t)il[nl * KNB + k] * CH + cg * 96;
        #pragma unroll
        for (int j = 0; j < 6; ++j){
            float4 v = *reinterpret_cast<const float4*>(cr + (sub + 4 * j) * 4);
            mx[j].x = fmaxf(mx[j].x, v.x - qv[j].x);
            mx[j].y = fmaxf(mx[j].y, v.y - qv[j].y);
            mx[j].z = fmaxf(mx[j].z, v.z - qv[j].z);
            mx[j].w = fmaxf(mx[j].w, v.w - qv[j].w);
        }
    }

    #pragma unroll
    for (int j = 0; j < 6; ++j){
        const int cb = (sub + 4 * j) * 4;
        float4 s4 = *reinterpret_cast<const float4*>(sh0 + cg * 96 + cb);
        float fi[4] = {qv[j].x + s4.x, qv[j].y + s4.y, qv[j].z + s4.z, qv[j].w + s4.w};
        float mm[4] = {mx[j].x, mx[j].y, mx[j].z, mx[j].w};
        #pragma unroll
        for (int e = 0; e < 4; ++e){
            int cl = cb + e;
            lt[(2 * cl) * 33 + nl]     = fi[e];
            lt[(2 * cl + 1) * 33 + nl] = mm[e];
        }
    }
    __syncthreads();

    const int rsub = tid >> 5;
    const int ni   = tid & 31;
    for (int r0 = 0; r0 < 192; r0 += 4){
        int row = r0 + rsub;
        int ch  = cg * 192 + row;
        hcat[((size_t)b * 2 * CH + ch) * NPT + n0 + ni] = lt[row * 33 + ni];
    }
}

// ---------------- mr-conv GEMM (K=384) + bias, with fused BN1-stat atomics ----------------------
__global__ __launch_bounds__(256) void k_gemm_mr(
    const float* __restrict__ in, const float* __restrict__ W, const float* __restrict__ bias,
    float* __restrict__ out, float* __restrict__ s1sum, float* __restrict__ s1sq)
{
    constexpr int KDIM = 2 * CH, OT = 8, NT = 4;
    __shared__ float wtT[KDIM][OT];
    __shared__ float redS[4][8], redQ[4][8];
    const int tid = threadIdx.x;
    const int o0  = blockIdx.y * OT;
    const int b   = blockIdx.z;
    const int n   = blockIdx.x * (256 * NT) + tid * NT;

    for (int lin = tid; lin < KDIM * OT; lin += 256){
        int c = lin >> 3, o = lin & 7;
        wtT[c][o] = W[(size_t)(o0 + o) * KDIM + c];
    }
    __syncthreads();

    float acc[OT][NT] = {};
    const float* ip = in + (size_t)b * KDIM * NPT + n;
    #pragma unroll 2
    for (int c = 0; c < KDIM; ++c){
        float4 x4 = *reinterpret_cast<const float4*>(ip + (size_t)c * NPT);
        float xv[NT] = {x4.x, x4.y, x4.z, x4.w};
        float4 w0 = *reinterpret_cast<const float4*>(&wtT[c][0]);
        float4 w1 = *reinterpret_cast<const float4*>(&wtT[c][4]);
        float wv[OT] = {w0.x, w0.y, w0.z, w0.w, w1.x, w1.y, w1.z, w1.w};
        #pragma unroll
        for (int oo = 0; oo < OT; ++oo)
            #pragma unroll
            for (int j = 0; j < NT; ++j)
                acc[oo][j] = fmaf(wv[oo], xv[j], acc[oo][j]);
    }

    float ps[OT], pq[OT];
    #pragma unroll
    for (int oo = 0; oo < OT; ++oo){
        size_t off = ((size_t)b * CH + o0 + oo) * NPT + n;
        float add = bias[o0 + oo];
        float vals[4];
        float s = 0.f, q = 0.f;
        #pragma unroll
        for (int j = 0; j < 4; ++j){
            vals[j] = acc[oo][j] + add;
            s += vals[j];
            q = fmaf(vals[j], vals[j], q);
        }
        ps[oo] = s; pq[oo] = q;
        float4 o4; o4.x = vals[0]; o4.y = vals[1]; o4.z = vals[2]; o4.w = vals[3];
        *reinterpret_cast<float4*>(out + off) = o4;
    }

    #pragma unroll
    for (int oo = 0; oo < OT; ++oo){
        #pragma unroll
        for (int off = 32; off; off >>= 1){
            ps[oo] += __shfl_xor(ps[oo], off);
            pq[oo] += __shfl_xor(pq[oo], off);
        }
    }
    const int wv = tid >> 6, lane = tid & 63;
    if (lane == 0){
        #pragma unroll
        for (int oo = 0; oo < OT; ++oo){ redS[wv][oo] = ps[oo]; redQ[wv][oo] = pq[oo]; }
    }
    __syncthreads();
    if (tid < 8){
        float s = redS[0][tid] + redS[1][tid] + redS[2][tid] + redS[3][tid];
        float q = redQ[0][tid] + redQ[1][tid] + redQ[2][tid] + redQ[3][tid];
        atomicAdd(&s1sum[o0 + tid], s);
        atomicAdd(&s1sq[o0 + tid], q);
    }
}

// ---------------- u = gelu(gelu(BN1(t2))), BN1 from sums; fused BN2-stat atomics ----------------
__global__ __launch_bounds__(256) void k_u(
    const float* __restrict__ in, const float* __restrict__ s1sum, const float* __restrict__ s1sq,
    const float* __restrict__ gm, const float* __restrict__ bm,
    float* __restrict__ out, float* __restrict__ s2sum, float* __restrict__ s2sq)
{
    __shared__ float redS[4], redQ[4];
    const int c = blockIdx.y, b = blockIdx.z;
    const int n = (blockIdx.x * 256 + threadIdx.x) * 4;
    const float invn = 1.0f / NTOT;
    float mean = s1sum[c] * invn;
    float var  = s1sq[c] * invn - mean * mean;
    float rstd = rsqrtf(var + 1e-5f);
    float s = rstd * gm[c], t = bm[c] - mean * s;

    size_t i = ((size_t)b * CH + c) * NPT + n;
    float4 v = *reinterpret_cast<const float4*>(in + i);
    float4 o;
    o.x = gelu_exact(gelu_exact(fmaf(v.x, s, t)));
    o.y = gelu_exact(gelu_exact(fmaf(v.y, s, t)));
    o.z = gelu_exact(gelu_exact(fmaf(v.z, s, t)));
    o.w = gelu_exact(gelu_exact(fmaf(v.w, s, t)));
    *reinterpret_cast<float4*>(out + i) = o;

    float ps = o.x + o.y + o.z + o.w;
    float pq = fmaf(o.x, o.x, fmaf(o.y, o.y, fmaf(o.z, o.z, o.w * o.w)));
    #pragma unroll
    for (int off = 32; off; off >>= 1){
        ps += __shfl_xor(ps, off);
        pq += __shfl_xor(pq, off);
    }
    const int wv = threadIdx.x >> 6, lane = threadIdx.x & 63;
    if (lane == 0){ redS[wv] = ps; redQ[wv] = pq; }
    __syncthreads();
    if (threadIdx.x == 0){
        atomicAdd(&s2sum[c], redS[0] + redS[1] + redS[2] + redS[3]);
        atomicAdd(&s2sq[c],  redQ[0] + redQ[1] + redQ[2] + redQ[3]);
    }
}

// ---------------- fc2 GEMM with BN2 (from sums) folded into input + residual --------------------
__global__ __launch_bounds__(256) void k_gemm_fc2(
    const float* __restrict__ in, const float* __restrict__ W,
    const float* __restrict__ s2sum, const float* __restrict__ s2sq,
    const float* __restrict__ g1, const float* __restrict__ b1,
    const float* __restrict__ resid, float* __restrict__ out)
{
    constexpr int KDIM = CH, OT = 8, NT = 4;
    __shared__ float wtT[KDIM][OT];
    __shared__ float scl[KDIM], shl[KDIM];
    const int tid = threadIdx.x;
    const int o0  = blockIdx.y * OT;
    const int b   = blockIdx.z;
    const int n   = blockIdx.x * (256 * NT) + tid * NT;

    for (int lin = tid; lin < KDIM * OT; lin += 256){
        int c = lin >> 3, o = lin & 7;
        wtT[c][o] = W[(size_t)(o0 + o) * KDIM + c];
    }
    const float invn = 1.0f / NTOT;
    for (int c = tid; c < KDIM; c += 256){
        float mean = s2sum[c] * invn;
        float var  = s2sq[c] * invn - mean * mean;
        float rstd = rsqrtf(var + 1e-5f);
        float s = rstd * g1[c];
        scl[c] = s;
        shl[c] = b1[c] - mean * s;
    }
    __syncthreads();

    float acc[OT][NT] = {};
    const float* ip = in + (size_t)b * KDIM * NPT + n;
    #pragma unroll 2
    for (int c = 0; c < KDIM; ++c){
        float4 x4 = *reinterpret_cast<const float4*>(ip + (size_t)c * NPT);
        float xv[NT];
        xv[0] = fmaf(x4.x, scl[c], shl[c]);
        xv[1] = fmaf(x4.y, scl[c], shl[c]);
        xv[2] = fmaf(x4.z, scl[c], shl[c]);
        xv[3] = fmaf(x4.w, scl[c], shl[c]);
        float4 w0 = *reinterpret_cast<const float4*>(&wtT[c][0]);
        float4 w1 = *reinterpret_cast<const float4*>(&wtT[c][4]);
        float wv[OT] = {w0.x, w0.y, w0.z, w0.w, w1.x, w1.y, w1.z, w1.w};
        #pragma unroll
        for (int oo = 0; oo < OT; ++oo)
            #pragma unroll
            for (int j = 0; j < NT; ++j)
                acc[oo][j] = fmaf(wv[oo], xv[j], acc[oo][j]);
    }

    #pragma unroll
    for (int oo = 0; oo < OT; ++oo){
        size_t off = ((size_t)b * CH + o0 + oo) * NPT + n;
        float4 r4 = *reinterpret_cast<const float4*>(resid + off);
        float4 o4;
        o4.x = acc[oo][0] + r4.x; o4.y = acc[oo][1] + r4.y;
        o4.z = acc[oo][2] + r4.z; o4.w = acc[oo][3] + r4.w;
        *reinterpret_cast<float4*>(out + off) = o4;
    }
}

extern "C" void kernel_launch(void* const* d_in, const int* in_sizes, int n_in,
                              void* d_out, int out_size, void* d_ws, size_t ws_size,
                              hipStream_t stream)
{
    const float* x    = (const float*)d_in[0];
    const float* w1   = (const float*)d_in[1];
    const float* w2   = (const float*)d_in[2];
    const float* wmr  = (const float*)d_in[3];
    const float* bmr  = (const float*)d_in[4];
    const float* g0   = (const float*)d_in[5];
    const float* b0   = (const float*)d_in[6];
    const float* gm   = (const float*)d_in[7];
    const float* bm   = (const float*)d_in[8];
    const float* g1   = (const float*)d_in[9];
    const float* b1   = (const float*)d_in[10];
    float* outp = (float*)d_out;

    const size_t BCN = (size_t)BSZ * CH * NPT;
    float*  A      = (float*)d_ws;                       // BCN f32: t2
    float*  Bb     = A + BCN;                            // BCN f32: featbf (bf16) -> u
    unsigned short* featbf = (unsigned short*)Bb;
    float*  Cc     = Bb + BCN;                           // 2*BCN f32: t1d (f64) -> hcat
    double* t1d    = (double*)Cc;
    double* featT  = (double*)(Cc + 2 * BCN);            // BCN f64
    float*  feat32 = (float*)(featT + BCN);              // BCN f32
    float*  sqv    = feat32 + BCN;                       // B*N
    int*    idxh   = (int*)(sqv + (size_t)BSZ * NPT);    // B*N*40
    int*    idxf   = idxh + (size_t)BSZ * NPT * KCAND;   // B*N*16
    float*  bnacc  = (float*)(idxf + (size_t)BSZ * NPT * KNB);  // 4*CH f32
    float *s1sum = bnacc, *s1sq = bnacc + CH, *s2sum = bnacc + 2 * CH, *s2sq = bnacc + 3 * CH;
    double* scd    = (double*)(bnacc + 4 * CH);
    float*  scb    = (float*)(scd + CH);
    float *sc0 = scb, *sh0 = scb + CH;

    dim3 gg(NPT / 1024, CH / 8, BSZ);
    dim3 ge(NPT / 1024, CH, BSZ);

    hipMemsetAsync(bnacc, 0, 4 * CH * sizeof(float), stream);
    // fc1 (f64 accumulate)
    k_fc1_f64<<<gg, 256, 0, stream>>>(x, w1, t1d);
    // BN0 stats in f64
    k_stats_f64<<<CH, 256, 0, stream>>>(t1d, g0, b0, sc0, sh0, scd);
    // fused transpose/scale -> featT + feat32 + featbf + sqv
    k_feat<<<dim3(NPT / 32, BSZ), dim3(32, 8), 0, stream>>>(t1d, scd, featT, feat32, featbf, sqv);
    // kNN prefilter (single-list minimal-register variant)
    k_knn_mfma<<<dim3(2 * NPT / 32, BSZ), 256, 0, stream>>>(featbf, sqv, idxh);
    // fused refine (fp32 + certified f64 fallback)
    k_refine<<<dim3(NPT, BSZ), 64, 0, stream>>>(feat32, featT, idxh, idxf);
    // gather (coalesced; writes hcat over dead t1d)
    k_gather2<<<dim3(NPT / 32, 2, BSZ), 128, 0, stream>>>(feat32, sh0, idxf, Cc);
    // mr conv + bias + BN1-stat atomics
    k_gemm_mr<<<gg, 256, 0, stream>>>(Cc, wmr, bmr, A, s1sum, s1sq);
    // u = gelu(gelu(BN1(t2))) + BN2-stat atomics
    k_u<<<ge, 256, 0, stream>>>(A, s1sum, s1sq, gm, bm, Bb, s2sum, s2sq);
    // fc2 with BN2 folded + residual
    k_gemm_fc2<<<gg, 256, 0, stream>>>(Bb, w2, s2sum, s2sq, g1, b1, x, outp);
}